// Round 1
// baseline (1080.599 us; speedup 1.0000x reference)
//
#include <hip/hip_runtime.h>
#include <math.h>

// Problem constants
#define NSEQ 2048
#define DMOD 1024
#define NBATCH 4
#define NHEAD 16
#define DHEAD 64
#define NFREQ 1025
#define NANCH 32

__device__ __forceinline__ float gelu_exact(float x) {
  return 0.5f * x * (1.0f + erff(x * 0.70710678118654752440f));
}

// ---------------- GEMM: C = A(MxK) @ B(KxN) + bias[, gelu] ----------------
template<bool GELU>
__global__ __launch_bounds__(256) void gemm_bias_kernel(
    const float* __restrict__ A, const float* __restrict__ B,
    const float* __restrict__ bias, float* __restrict__ C,
    int M, int N, int K) {
  __shared__ float As[64][20];   // 64 x 16 tile, row stride 20 (16B-aligned rows)
  __shared__ float Bs[16][64];
  const int tid = threadIdx.x;
  const int m0 = blockIdx.y * 64, n0 = blockIdx.x * 64;
  const int tx = tid & 15, ty = tid >> 4;
  const int ar = tid >> 2, ak = (tid & 3) * 4;
  const int br = tid >> 4, bn = (tid & 15) * 4;
  float acc[4][4] = {};
  for (int k0 = 0; k0 < K; k0 += 16) {
    float4 av = *reinterpret_cast<const float4*>(&A[(size_t)(m0 + ar) * K + k0 + ak]);
    float4 bvv = *reinterpret_cast<const float4*>(&B[(size_t)(k0 + br) * N + n0 + bn]);
    *reinterpret_cast<float4*>(&As[ar][ak]) = av;
    *reinterpret_cast<float4*>(&Bs[br][bn]) = bvv;
    __syncthreads();
#pragma unroll
    for (int kk = 0; kk < 16; ++kk) {
      float a[4], b[4];
#pragma unroll
      for (int i = 0; i < 4; ++i) a[i] = As[ty * 4 + i][kk];
#pragma unroll
      for (int j = 0; j < 4; ++j) b[j] = Bs[kk][tx * 4 + j];
#pragma unroll
      for (int i = 0; i < 4; ++i)
#pragma unroll
        for (int j = 0; j < 4; ++j)
          acc[i][j] = fmaf(a[i], b[j], acc[i][j]);
    }
    __syncthreads();
  }
#pragma unroll
  for (int i = 0; i < 4; ++i) {
    int m = m0 + ty * 4 + i;
#pragma unroll
    for (int j = 0; j < 4; ++j) {
      int n = n0 + tx * 4 + j;
      float cv = acc[i][j] + bias[n];
      if (GELU) cv = gelu_exact(cv);
      C[(size_t)m * N + n] = cv;
    }
  }
}

// ---------------- scores s = h1 @ Wp2 + bp2 (K=256) ----------------
__global__ __launch_bounds__(256) void score_kernel(
    const float* __restrict__ h1, const float* __restrict__ Wp2,
    const float* __restrict__ bp2, float* __restrict__ s) {
  int tid = threadIdx.x;
  int lane = tid & 63, w = tid >> 6;
  int row = blockIdx.x * 4 + w;
  float acc = 0.f;
#pragma unroll
  for (int q = 0; q < 4; ++q) {
    int k = lane + 64 * q;
    acc = fmaf(h1[(size_t)row * 256 + k], Wp2[k], acc);
  }
#pragma unroll
  for (int off = 32; off; off >>= 1) acc += __shfl_down(acc, off);
  if (lane == 0) s[row] = acc + bp2[0];
}

// ---------------- per-batch softmax stats (max, sumexp) ----------------
__global__ __launch_bounds__(256) void softmax_stats_kernel(
    const float* __restrict__ s, float* __restrict__ bstats) {
  int b = blockIdx.x, tid = threadIdx.x;
  __shared__ float red[256];
  float m = -1e30f;
  for (int n = tid; n < NSEQ; n += 256) m = fmaxf(m, s[b * NSEQ + n]);
  red[tid] = m; __syncthreads();
  for (int o = 128; o; o >>= 1) { if (tid < o) red[tid] = fmaxf(red[tid], red[tid + o]); __syncthreads(); }
  float bm = red[0]; __syncthreads();
  float sum = 0.f;
  for (int n = tid; n < NSEQ; n += 256) sum += expf(s[b * NSEQ + n] - bm);
  red[tid] = sum; __syncthreads();
  for (int o = 128; o; o >>= 1) { if (tid < o) red[tid] += red[tid + o]; __syncthreads(); }
  if (tid == 0) { bstats[b * 2] = bm; bstats[b * 2 + 1] = red[0]; }
}

// ---------------- pooled g: partial sums over n-chunks (deterministic) ----------------
__global__ __launch_bounds__(256) void pool_partial_kernel(
    const float* __restrict__ x, const float* __restrict__ s,
    const float* __restrict__ bstats, float* __restrict__ gpart) {
  int chunk = blockIdx.x, b = blockIdx.y;   // grid (16, 4)
  int tid = threadIdx.x;
  __shared__ float wsh[128];
  float bm = bstats[b * 2], inv = 1.0f / bstats[b * 2 + 1];
  int n0 = chunk * 128;
  if (tid < 128) wsh[tid] = expf(s[b * NSEQ + n0 + tid] - bm) * inv;
  __syncthreads();
  float acc[4] = {};
  for (int n = 0; n < 128; ++n) {
    float wn = wsh[n];
    const float* xr = &x[((size_t)b * NSEQ + n0 + n) * DMOD];
#pragma unroll
    for (int q = 0; q < 4; ++q) acc[q] = fmaf(wn, xr[tid + 256 * q], acc[q]);
  }
  float* gp = &gpart[((size_t)b * 16 + chunk) * DMOD];
#pragma unroll
  for (int q = 0; q < 4; ++q) gp[tid + 256 * q] = acc[q];
}

__global__ __launch_bounds__(256) void pool_reduce_kernel(
    const float* __restrict__ gpart, float* __restrict__ g) {
  int b = blockIdx.x, tid = threadIdx.x;
  for (int d = tid; d < DMOD; d += 256) {
    float acc = 0.f;
    for (int c = 0; c < 16; ++c) acc += gpart[((size_t)b * 16 + c) * DMOD + d];
    g[b * DMOD + d] = acc;
  }
}

// ---------------- gate MLP -> anchors (B,H,A,2) flat as (b, 1024) ----------------
__global__ __launch_bounds__(256) void gate_mlp_kernel(
    const float* __restrict__ g, const float* __restrict__ Wg1,
    const float* __restrict__ bg1, const float* __restrict__ Wg2,
    const float* __restrict__ bg2, float* __restrict__ anchors) {
  int b = blockIdx.x, tid = threadIdx.x;
  __shared__ float gs[1024];
  __shared__ float hs[256];
  for (int d = tid; d < 1024; d += 256) gs[d] = g[b * 1024 + d];
  __syncthreads();
  float acc = bg1[tid];
  for (int i = 0; i < 1024; ++i) acc = fmaf(gs[i], Wg1[i * 256 + tid], acc);
  hs[tid] = gelu_exact(acc);
  __syncthreads();
#pragma unroll
  for (int q = 0; q < 4; ++q) {
    int c = tid + 256 * q;
    float a2 = bg2[c];
    for (int i = 0; i < 256; ++i) a2 = fmaf(hs[i], Wg2[i * 1024 + c], a2);
    anchors[b * 1024 + c] = a2;
  }
}

// ---------------- cubic resize + modReLU + complex circular conv ----------------
__device__ __forceinline__ float keys_cubic(float x) {
  // Keys kernel, a = -0.5 (jax _fill_keys_cubic_kernel)
  if (x >= 2.0f) return 0.0f;
  if (x >= 1.0f) return ((-0.5f * x + 2.5f) * x - 4.0f) * x + 2.0f;
  return ((1.5f * x - 2.5f) * x) * x + 1.0f;
}

__global__ __launch_bounds__(256) void gate_kernel(
    const float* __restrict__ anchors, const float* __restrict__ mod_bias,
    const float* __restrict__ kr5, const float* __restrict__ ki5,
    float* __restrict__ gate_out /* (B*H, F, 2) */) {
  int bh = blockIdx.x;
  int tid = threadIdx.x;
  __shared__ float ar_[32], ai_[32];
  __shared__ float gr[NFREQ], gi[NFREQ];
  if (tid < 32) {
    ar_[tid] = anchors[bh * 64 + tid * 2 + 0];
    ai_[tid] = anchors[bh * 64 + tid * 2 + 1];
  }
  __syncthreads();
  const float inv_scale = 32.0f / 1025.0f;
  for (int f = tid; f < NFREQ; f += 256) {
    // jax.image.resize cubic: half-pixel sample, Keys a=-0.5, renormalized edge taps
    float c = (f + 0.5f) * inv_scale - 0.5f;
    int j0 = (int)floorf(c) - 1;
    float wr = 0.f, wi = 0.f, wsum = 0.f;
#pragma unroll
    for (int u = 0; u < 4; ++u) {
      int j = j0 + u;
      if (j < 0 || j > 31) continue;
      float w = keys_cubic(fabsf(c - (float)j));
      wsum += w;
      wr = fmaf(w, ar_[j], wr);
      wi = fmaf(w, ai_[j], wi);
    }
    float invw = 1.0f / wsum;
    wr *= invw; wi *= invw;
    // modReLU
    float mag = sqrtf(wr * wr + wi * wi);
    float scale = fmaxf(mag + mod_bias[f], 0.0f) / (mag + 1e-8f);
    gr[f] = wr * scale;
    gi[f] = wi * scale;
  }
  __syncthreads();
  float k_r[5], k_i[5];
#pragma unroll
  for (int j = 0; j < 5; ++j) { k_r[j] = kr5[j]; k_i[j] = ki5[j]; }
  for (int f = tid; f < NFREQ; f += 256) {
    float cr = 0.f, ci = 0.f;
#pragma unroll
    for (int j = 0; j < 5; ++j) {
      int idx = f + j - 2;
      if (idx < 0) idx += NFREQ;
      else if (idx >= NFREQ) idx -= NFREQ;
      float a = gr[idx], bb = gi[idx];
      cr = fmaf(k_r[j], a, cr); cr = fmaf(-k_i[j], bb, cr);
      ci = fmaf(k_r[j], bb, ci); ci = fmaf(k_i[j], a, ci);
    }
    gate_out[((size_t)bh * NFREQ + f) * 2 + 0] = cr;
    gate_out[((size_t)bh * NFREQ + f) * 2 + 1] = ci;
  }
}

// ---------------- k_time[bh,t] = irfft(gate[bh,:], n=2048) via direct DFT ----------------
__global__ __launch_bounds__(256) void ktime_kernel(
    const float* __restrict__ gate_out, float* __restrict__ kt) {
  int bh = blockIdx.x, tq = blockIdx.y;
  int tid = threadIdx.x;
  __shared__ float cr[NFREQ], ci[NFREQ];
  __shared__ float ct[NSEQ], st[NSEQ];
  for (int f = tid; f < NFREQ; f += 256) {
    cr[f] = gate_out[((size_t)bh * NFREQ + f) * 2 + 0];
    ci[f] = gate_out[((size_t)bh * NFREQ + f) * 2 + 1];
  }
  const float w0 = 6.283185307179586476925f / 2048.0f;
  for (int m = tid; m < NSEQ; m += 256) {
    float th = w0 * (float)m;
    ct[m] = cosf(th);
    st[m] = sinf(th);
  }
  __syncthreads();
  int t = tq * 256 + tid;
  // irfft convention: real parts only at DC and Nyquist
  float acc0 = cr[0] + cr[1024] * ((t & 1) ? -1.0f : 1.0f);
  float acc2 = 0.f;
  for (int f = 1; f < 1024; ++f) {
    int m = (f * t) & 2047;
    acc2 = fmaf(cr[f], ct[m], acc2);
    acc2 = fmaf(-ci[f], st[m], acc2);
  }
  kt[(size_t)bh * NSEQ + t] = (acc0 + 2.0f * acc2) * (1.0f / 2048.0f);
}

// ---------------- circular conv: y[b,t,c] = sum_s k[b,c>>6,(t-s)&2047] * v[b,s,c] ----------------
__global__ __launch_bounds__(256) void circconv_kernel(
    const float* __restrict__ v, const float* __restrict__ kt,
    float* __restrict__ y) {
  // grid: (DMOD/64=16, NSEQ/64=32, B=4)
  __shared__ float vs[64][68];
  __shared__ float ks[128];
  int tid = threadIdx.x;
  int c0 = blockIdx.x * 64, t0 = blockIdx.y * 64, b = blockIdx.z;
  int h = c0 >> 6;
  const float* kbh = &kt[((size_t)b * NHEAD + h) * NSEQ];
  int tx = tid & 15, ty = tid >> 4;
  int lr = tid >> 4, lc = (tid & 15) * 4;
  float acc[4][4] = {};
  for (int s0 = 0; s0 < NSEQ; s0 += 64) {
#pragma unroll
    for (int q = 0; q < 4; ++q) {
      int r = lr + q * 16;
      *reinterpret_cast<float4*>(&vs[r][lc]) =
          *reinterpret_cast<const float4*>(&v[(((size_t)b * NSEQ) + s0 + r) * DMOD + c0 + lc]);
    }
    if (tid < 128) ks[tid] = kbh[(t0 - s0 - 63 + tid) & 2047];
    __syncthreads();
#pragma unroll 4
    for (int ss = 0; ss < 64; ++ss) {
      float bvv[4], av[4];
#pragma unroll
      for (int j = 0; j < 4; ++j) bvv[j] = vs[ss][tx * 4 + j];
#pragma unroll
      for (int i = 0; i < 4; ++i) av[i] = ks[ty * 4 + i - ss + 63];
#pragma unroll
      for (int i = 0; i < 4; ++i)
#pragma unroll
        for (int j = 0; j < 4; ++j)
          acc[i][j] = fmaf(av[i], bvv[j], acc[i][j]);
    }
    __syncthreads();
  }
#pragma unroll
  for (int i = 0; i < 4; ++i) {
    int t = t0 + ty * 4 + i;
#pragma unroll
    for (int j = 0; j < 4; ++j)
      y[(((size_t)b * NSEQ) + t) * DMOD + c0 + tx * 4 + j] = acc[i][j];
  }
}

extern "C" void kernel_launch(void* const* d_in, const int* in_sizes, int n_in,
                              void* d_out, int out_size, void* d_ws, size_t ws_size,
                              hipStream_t stream) {
  const float* x        = (const float*)d_in[0];
  const float* Wv       = (const float*)d_in[1];
  const float* bv       = (const float*)d_in[2];
  const float* Wp1      = (const float*)d_in[3];
  const float* bp1      = (const float*)d_in[4];
  const float* Wp2      = (const float*)d_in[5];
  const float* bp2      = (const float*)d_in[6];
  const float* Wg1      = (const float*)d_in[7];
  const float* bg1      = (const float*)d_in[8];
  const float* Wg2      = (const float*)d_in[9];
  const float* bg2      = (const float*)d_in[10];
  const float* mod_bias = (const float*)d_in[11];
  const float* ckr      = (const float*)d_in[12];
  const float* cki      = (const float*)d_in[13];
  const float* Wo       = (const float*)d_in[14];
  const float* bo       = (const float*)d_in[15];
  float* out = (float*)d_out;
  float* ws  = (float*)d_ws;

  const int M = NBATCH * NSEQ;          // 8192
  float* v  = out;                      // (B,N,D) staged in d_out
  float* y  = ws;                       // (B,N,D)
  float* h1 = ws;                       // aliases y; dead before y written
  float* s       = ws + (size_t)M * DMOD;       // 8192
  float* bstats  = s + M;                       // 8
  float* gpart   = bstats + 8;                  // 4*16*1024
  float* g       = gpart + 4 * 16 * DMOD;       // 4096
  float* anchors = g + NBATCH * DMOD;           // 4096
  float* gate    = anchors + NBATCH * DMOD;     // 64*1025*2
  float* kt      = gate + NBATCH * NHEAD * NFREQ * 2; // 64*2048

  dim3 blk(256);
  // 1. v = x @ Wv + bv
  gemm_bias_kernel<false><<<dim3(DMOD / 64, M / 64), blk, 0, stream>>>(x, Wv, bv, v, M, DMOD, DMOD);
  // 2. h1 = gelu(x @ Wp1 + bp1)
  gemm_bias_kernel<true><<<dim3(256 / 64, M / 64), blk, 0, stream>>>(x, Wp1, bp1, h1, M, 256, DMOD);
  // 3. s = h1 @ Wp2 + bp2
  score_kernel<<<dim3(M / 4), blk, 0, stream>>>(h1, Wp2, bp2, s);
  // 4. softmax stats
  softmax_stats_kernel<<<dim3(NBATCH), blk, 0, stream>>>(s, bstats);
  // 5/6. pooled g (deterministic two-stage)
  pool_partial_kernel<<<dim3(16, NBATCH), blk, 0, stream>>>(x, s, bstats, gpart);
  pool_reduce_kernel<<<dim3(NBATCH), blk, 0, stream>>>(gpart, g);
  // 7. anchors
  gate_mlp_kernel<<<dim3(NBATCH), blk, 0, stream>>>(g, Wg1, bg1, Wg2, bg2, anchors);
  // 8. gate = conv(modrelu(cubic_resize(anchors)))
  gate_kernel<<<dim3(NBATCH * NHEAD), blk, 0, stream>>>(anchors, mod_bias, ckr, cki, gate);
  // 9. k_time = irfft(gate)
  ktime_kernel<<<dim3(NBATCH * NHEAD, NSEQ / 256), blk, 0, stream>>>(gate, kt);
  // 10. y = circular_conv(v, k_time)
  circconv_kernel<<<dim3(DMOD / 64, NSEQ / 64, NBATCH), blk, 0, stream>>>(v, kt, y);
  // 11. out = y @ Wo + bo
  gemm_bias_kernel<false><<<dim3(DMOD / 64, M / 64), blk, 0, stream>>>(y, Wo, bo, out, M, DMOD, DMOD);
}

// Round 2
// 543.185 us; speedup vs baseline: 1.9894x; 1.9894x over previous
//
#include <hip/hip_runtime.h>
#include <math.h>

#define NSEQ 2048
#define DMOD 1024
#define NBATCH 4
#define NHEAD 16
#define NFREQ 1025

typedef unsigned short u16t;
typedef __attribute__((ext_vector_type(8))) short short8;
typedef __attribute__((ext_vector_type(4))) float f32x4;

__device__ __forceinline__ float gelu_exact(float x) {
  return 0.5f * x * (1.0f + erff(x * 0.70710678118654752440f));
}
__device__ __forceinline__ u16t bf16_rtn(float x) {
  unsigned u = __float_as_uint(x);
  return (u16t)((u + 0x7FFFu + ((u >> 16) & 1u)) >> 16);
}
__device__ __forceinline__ float bf16f(u16t h) {
  return __uint_as_float(((unsigned)h) << 16);
}

// ---------------- elementwise split fp32 -> bf16 hi/lo ----------------
__global__ __launch_bounds__(256) void split_kernel(const float* __restrict__ in,
    u16t* __restrict__ hi, u16t* __restrict__ lo, int n8) {
  for (int i = blockIdx.x * blockDim.x + threadIdx.x; i < n8; i += gridDim.x * blockDim.x) {
    const float4* p = reinterpret_cast<const float4*>(in + (size_t)i * 8);
    float4 a = p[0], b = p[1];
    float vv[8] = {a.x, a.y, a.z, a.w, b.x, b.y, b.z, b.w};
    alignas(16) u16t th[8];
    alignas(16) u16t tl[8];
#pragma unroll
    for (int e = 0; e < 8; ++e) {
      u16t h = bf16_rtn(vv[e]);
      th[e] = h;
      tl[e] = bf16_rtn(vv[e] - bf16f(h));
    }
    *reinterpret_cast<uint4*>(hi + (size_t)i * 8) = *reinterpret_cast<const uint4*>(th);
    *reinterpret_cast<uint4*>(lo + (size_t)i * 8) = *reinterpret_cast<const uint4*>(tl);
  }
}

// ---------------- transpose + split weights: W[K][N] -> T{h,l}[N][K] ----------------
__global__ __launch_bounds__(256) void tsplit_kernel(const float* __restrict__ W,
    u16t* __restrict__ Th, u16t* __restrict__ Tl, int K, int N) {
  __shared__ float tile[32][33];
  int k0 = blockIdx.y * 32, n0 = blockIdx.x * 32;
  int r = threadIdx.x >> 5, c = threadIdx.x & 31;
#pragma unroll
  for (int i = 0; i < 4; ++i)
    tile[r + 8 * i][c] = W[(size_t)(k0 + r + 8 * i) * N + n0 + c];
  __syncthreads();
#pragma unroll
  for (int i = 0; i < 4; ++i) {
    int rr = r + 8 * i;
    float v = tile[c][rr];                      // = W[k0+c][n0+rr]
    u16t h = bf16_rtn(v);
    Th[(size_t)(n0 + rr) * K + k0 + c] = h;
    Tl[(size_t)(n0 + rr) * K + k0 + c] = bf16_rtn(v - bf16f(h));
  }
}

// ---------------- split-bf16 MFMA GEMM: C = A(MxK) @ B(KxN) + bias ----------------
// A given as hi/lo bf16 [M][K]; B given transposed hi/lo bf16 [N][K].
// OUTMODE 0: fp32 C. OUTMODE 1: split bf16 Ch/Cl.
template<bool GELU, int OUTMODE>
__global__ __launch_bounds__(256) void mfma_gemm(
    const u16t* __restrict__ Ah_g, const u16t* __restrict__ Al_g,
    const u16t* __restrict__ Bh_g, const u16t* __restrict__ Bl_g,
    const float* __restrict__ bias,
    float* __restrict__ Cf, u16t* __restrict__ Ch, u16t* __restrict__ Cl,
    int N, int K) {
  __shared__ u16t Ahs[128 * 32], Als[128 * 32], Bhs[128 * 32], Bls[128 * 32];
  const int tid = threadIdx.x;
  const int lane = tid & 63, wave = tid >> 6;
  const int wm0 = (wave >> 1) * 64, wn0 = (wave & 1) * 64;
  const int m0 = blockIdx.y * 128, n0 = blockIdx.x * 128;
  const int lr = lane & 15, lg = lane >> 4;
  const int srow_base = tid >> 2, sslot = tid & 3;

  f32x4 acc[4][4];
#pragma unroll
  for (int i = 0; i < 4; ++i)
#pragma unroll
    for (int j = 0; j < 4; ++j) acc[i][j] = 0.0f;

  for (int k0 = 0; k0 < K; k0 += 32) {
#pragma unroll
    for (int cc = 0; cc < 2; ++cc) {
      int row = cc * 64 + srow_base;
      int gl = sslot ^ ((row >> 1) & 3);           // logical k-slot for this physical slot
      size_t ga = (size_t)(m0 + row) * K + k0 + gl * 8;
      size_t gb = (size_t)(n0 + row) * K + k0 + gl * 8;
      *reinterpret_cast<uint4*>(&Ahs[row * 32 + sslot * 8]) = *reinterpret_cast<const uint4*>(&Ah_g[ga]);
      *reinterpret_cast<uint4*>(&Als[row * 32 + sslot * 8]) = *reinterpret_cast<const uint4*>(&Al_g[ga]);
      *reinterpret_cast<uint4*>(&Bhs[row * 32 + sslot * 8]) = *reinterpret_cast<const uint4*>(&Bh_g[gb]);
      *reinterpret_cast<uint4*>(&Bls[row * 32 + sslot * 8]) = *reinterpret_cast<const uint4*>(&Bl_g[gb]);
    }
    __syncthreads();
    short8 ah[4], al[4];
#pragma unroll
    for (int mi = 0; mi < 4; ++mi) {
      int ar = wm0 + mi * 16 + lr;
      int sl = lg ^ ((ar >> 1) & 3);
      ah[mi] = *reinterpret_cast<const short8*>(&Ahs[ar * 32 + sl * 8]);
      al[mi] = *reinterpret_cast<const short8*>(&Als[ar * 32 + sl * 8]);
    }
#pragma unroll
    for (int ni = 0; ni < 4; ++ni) {
      int br = wn0 + ni * 16 + lr;
      int sl = lg ^ ((br >> 1) & 3);
      short8 bh = *reinterpret_cast<const short8*>(&Bhs[br * 32 + sl * 8]);
      short8 bl = *reinterpret_cast<const short8*>(&Bls[br * 32 + sl * 8]);
#pragma unroll
      for (int mi = 0; mi < 4; ++mi) {
        acc[mi][ni] = __builtin_amdgcn_mfma_f32_16x16x32_bf16(ah[mi], bh, acc[mi][ni], 0, 0, 0);
        acc[mi][ni] = __builtin_amdgcn_mfma_f32_16x16x32_bf16(ah[mi], bl, acc[mi][ni], 0, 0, 0);
        acc[mi][ni] = __builtin_amdgcn_mfma_f32_16x16x32_bf16(al[mi], bh, acc[mi][ni], 0, 0, 0);
      }
    }
    __syncthreads();
  }
#pragma unroll
  for (int mi = 0; mi < 4; ++mi)
#pragma unroll
    for (int ni = 0; ni < 4; ++ni) {
      int col = n0 + wn0 + ni * 16 + lr;
      float bv = bias[col];
      f32x4 a = acc[mi][ni];
#pragma unroll
      for (int r = 0; r < 4; ++r) {
        int row = m0 + wm0 + mi * 16 + lg * 4 + r;
        float val = a[r] + bv;
        if (GELU) val = gelu_exact(val);
        if (OUTMODE == 0) {
          Cf[(size_t)row * N + col] = val;
        } else {
          u16t h = bf16_rtn(val);
          Ch[(size_t)row * N + col] = h;
          Cl[(size_t)row * N + col] = bf16_rtn(val - bf16f(h));
        }
      }
    }
}

// ---------------- circular conv via MFMA on circulant tiles ----------------
// y[b,t,c] = sum_s kt[b,h(c),(t-s)&2047] * v[b,s,c], split-bf16 in, split-bf16 out.
__global__ __launch_bounds__(256) void circconv_mfma(
    const u16t* __restrict__ v_hi, const u16t* __restrict__ v_lo,
    const u16t* __restrict__ kt_h, const u16t* __restrict__ kt_l,
    u16t* __restrict__ y_hi, u16t* __restrict__ y_lo) {
  __shared__ u16t Bth[64 * 32], Btl[64 * 32];
  __shared__ u16t Wh[160], Wl[160];
  const int tid = threadIdx.x;
  const int lane = tid & 63, wave = tid >> 6;
  const int lr = lane & 15, lg = lane >> 4;
  const int t0 = blockIdx.x * 128;
  const int bh = blockIdx.y;
  const int b = bh >> 4, h = bh & 15;
  const int c0 = h * 64;
  const u16t* kh = kt_h + (size_t)bh * NSEQ;
  const u16t* kl = kt_l + (size_t)bh * NSEQ;
  const size_t vbase = (size_t)b * NSEQ * DMOD;
  const int jj = tid & 31, nb = (tid >> 5) * 8;

  f32x4 acc[2][4];
#pragma unroll
  for (int i = 0; i < 2; ++i)
#pragma unroll
    for (int j = 0; j < 4; ++j) acc[i][j] = 0.0f;

  for (int s0 = 0; s0 < NSEQ; s0 += 32) {
    if (tid < 160) {
      int idx = (t0 - s0 - 31 + tid) & 2047;      // two's-complement & = mod 2048
      Wh[tid] = kh[idx];
      Wl[tid] = kl[idx];
    }
    {
      // stage B^T tile with K-step reversal: Bt[n][j] = v[s0+31-j][c0+n]
      int srow = s0 + 31 - jj;
      uint4 hv = *reinterpret_cast<const uint4*>(&v_hi[vbase + (size_t)srow * DMOD + c0 + nb]);
      uint4 lv = *reinterpret_cast<const uint4*>(&v_lo[vbase + (size_t)srow * DMOD + c0 + nb]);
      const u16t* hvp = reinterpret_cast<const u16t*>(&hv);
      const u16t* lvp = reinterpret_cast<const u16t*>(&lv);
      int slot = jj >> 3, jrem = jj & 7;
#pragma unroll
      for (int e = 0; e < 8; ++e) {
        int n = nb + e;
        int pc = ((slot ^ ((n >> 1) & 3)) << 3) | jrem;
        Bth[n * 32 + pc] = hvp[e];
        Btl[n * 32 + pc] = lvp[e];
      }
    }
    __syncthreads();
    // A fragments straight out of the kt window: A[t][kappa(j)] = W[(t-t0)+j]
    short8 afh[2], afl[2];
#pragma unroll
    for (int mi = 0; mi < 2; ++mi) {
      int base = wave * 32 + mi * 16 + lr + lg * 8;
#pragma unroll
      for (int e = 0; e < 8; ++e) {
        afh[mi][e] = (short)Wh[base + e];
        afl[mi][e] = (short)Wl[base + e];
      }
    }
#pragma unroll
    for (int ni = 0; ni < 4; ++ni) {
      int br = ni * 16 + lr;
      int sl = lg ^ ((br >> 1) & 3);
      short8 bfh = *reinterpret_cast<const short8*>(&Bth[br * 32 + sl * 8]);
      short8 bfl = *reinterpret_cast<const short8*>(&Btl[br * 32 + sl * 8]);
#pragma unroll
      for (int mi = 0; mi < 2; ++mi) {
        acc[mi][ni] = __builtin_amdgcn_mfma_f32_16x16x32_bf16(afh[mi], bfh, acc[mi][ni], 0, 0, 0);
        acc[mi][ni] = __builtin_amdgcn_mfma_f32_16x16x32_bf16(afh[mi], bfl, acc[mi][ni], 0, 0, 0);
        acc[mi][ni] = __builtin_amdgcn_mfma_f32_16x16x32_bf16(afl[mi], bfh, acc[mi][ni], 0, 0, 0);
      }
    }
    __syncthreads();
  }
#pragma unroll
  for (int mi = 0; mi < 2; ++mi)
#pragma unroll
    for (int ni = 0; ni < 4; ++ni) {
#pragma unroll
      for (int r = 0; r < 4; ++r) {
        int t = t0 + wave * 32 + mi * 16 + lg * 4 + r;
        int c = c0 + ni * 16 + lr;
        size_t o = (size_t)(b * NSEQ + t) * DMOD + c;
        float val = acc[mi][ni][r];
        u16t hh = bf16_rtn(val);
        y_hi[o] = hh;
        y_lo[o] = bf16_rtn(val - bf16f(hh));
      }
    }
}

// ---------------- scores s = h1 @ Wp2 + bp2 (K=256) ----------------
__global__ __launch_bounds__(256) void score_kernel(
    const float* __restrict__ h1, const float* __restrict__ Wp2,
    const float* __restrict__ bp2, float* __restrict__ s) {
  int tid = threadIdx.x;
  int lane = tid & 63, w = tid >> 6;
  int row = blockIdx.x * 4 + w;
  float acc = 0.f;
#pragma unroll
  for (int q = 0; q < 4; ++q) {
    int k = lane + 64 * q;
    acc = fmaf(h1[(size_t)row * 256 + k], Wp2[k], acc);
  }
#pragma unroll
  for (int off = 32; off; off >>= 1) acc += __shfl_down(acc, off);
  if (lane == 0) s[row] = acc + bp2[0];
}

// ---------------- per-batch softmax stats ----------------
__global__ __launch_bounds__(256) void softmax_stats_kernel(
    const float* __restrict__ s, float* __restrict__ bstats) {
  int b = blockIdx.x, tid = threadIdx.x;
  __shared__ float red[256];
  float m = -1e30f;
  for (int n = tid; n < NSEQ; n += 256) m = fmaxf(m, s[b * NSEQ + n]);
  red[tid] = m; __syncthreads();
  for (int o = 128; o; o >>= 1) { if (tid < o) red[tid] = fmaxf(red[tid], red[tid + o]); __syncthreads(); }
  float bm = red[0]; __syncthreads();
  float sum = 0.f;
  for (int n = tid; n < NSEQ; n += 256) sum += expf(s[b * NSEQ + n] - bm);
  red[tid] = sum; __syncthreads();
  for (int o = 128; o; o >>= 1) { if (tid < o) red[tid] += red[tid + o]; __syncthreads(); }
  if (tid == 0) { bstats[b * 2] = bm; bstats[b * 2 + 1] = red[0]; }
}

// ---------------- pooled g: deterministic two-stage ----------------
__global__ __launch_bounds__(256) void pool_partial_kernel(
    const float* __restrict__ x, const float* __restrict__ s,
    const float* __restrict__ bstats, float* __restrict__ gpart) {
  int chunk = blockIdx.x, b = blockIdx.y;
  int tid = threadIdx.x;
  __shared__ float wsh[128];
  float bm = bstats[b * 2], inv = 1.0f / bstats[b * 2 + 1];
  int n0 = chunk * 128;
  if (tid < 128) wsh[tid] = expf(s[b * NSEQ + n0 + tid] - bm) * inv;
  __syncthreads();
  float acc[4] = {};
  for (int n = 0; n < 128; ++n) {
    float wn = wsh[n];
    const float* xr = &x[((size_t)b * NSEQ + n0 + n) * DMOD];
#pragma unroll
    for (int q = 0; q < 4; ++q) acc[q] = fmaf(wn, xr[tid + 256 * q], acc[q]);
  }
  float* gp = &gpart[((size_t)b * 16 + chunk) * DMOD];
#pragma unroll
  for (int q = 0; q < 4; ++q) gp[tid + 256 * q] = acc[q];
}

__global__ __launch_bounds__(256) void pool_reduce_kernel(
    const float* __restrict__ gpart, float* __restrict__ g) {
  int b = blockIdx.x, tid = threadIdx.x;
  for (int d = tid; d < DMOD; d += 256) {
    float acc = 0.f;
    for (int c = 0; c < 16; ++c) acc += gpart[((size_t)b * 16 + c) * DMOD + d];
    g[b * DMOD + d] = acc;
  }
}

// ---------------- gate MLP -> anchors ----------------
__global__ __launch_bounds__(256) void gate_mlp_kernel(
    const float* __restrict__ g, const float* __restrict__ Wg1,
    const float* __restrict__ bg1, const float* __restrict__ Wg2,
    const float* __restrict__ bg2, float* __restrict__ anchors) {
  int b = blockIdx.x, tid = threadIdx.x;
  __shared__ float gs[1024];
  __shared__ float hs[256];
  for (int d = tid; d < 1024; d += 256) gs[d] = g[b * 1024 + d];
  __syncthreads();
  float acc = bg1[tid];
  for (int i = 0; i < 1024; ++i) acc = fmaf(gs[i], Wg1[i * 256 + tid], acc);
  hs[tid] = gelu_exact(acc);
  __syncthreads();
#pragma unroll
  for (int q = 0; q < 4; ++q) {
    int c = tid + 256 * q;
    float a2 = bg2[c];
    for (int i = 0; i < 256; ++i) a2 = fmaf(hs[i], Wg2[i * 1024 + c], a2);
    anchors[b * 1024 + c] = a2;
  }
}

// ---------------- cubic resize + modReLU + complex circular conv ----------------
__device__ __forceinline__ float keys_cubic(float x) {
  if (x >= 2.0f) return 0.0f;
  if (x >= 1.0f) return ((-0.5f * x + 2.5f) * x - 4.0f) * x + 2.0f;
  return ((1.5f * x - 2.5f) * x) * x + 1.0f;
}

__global__ __launch_bounds__(256) void gate_kernel(
    const float* __restrict__ anchors, const float* __restrict__ mod_bias,
    const float* __restrict__ kr5, const float* __restrict__ ki5,
    float* __restrict__ gate_out) {
  int bh = blockIdx.x;
  int tid = threadIdx.x;
  __shared__ float ar_[32], ai_[32];
  __shared__ float gr[NFREQ], gi[NFREQ];
  if (tid < 32) {
    ar_[tid] = anchors[bh * 64 + tid * 2 + 0];
    ai_[tid] = anchors[bh * 64 + tid * 2 + 1];
  }
  __syncthreads();
  const float inv_scale = 32.0f / 1025.0f;
  for (int f = tid; f < NFREQ; f += 256) {
    float c = (f + 0.5f) * inv_scale - 0.5f;
    int j0 = (int)floorf(c) - 1;
    float wr = 0.f, wi = 0.f, wsum = 0.f;
#pragma unroll
    for (int u = 0; u < 4; ++u) {
      int j = j0 + u;
      if (j < 0 || j > 31) continue;
      float w = keys_cubic(fabsf(c - (float)j));
      wsum += w;
      wr = fmaf(w, ar_[j], wr);
      wi = fmaf(w, ai_[j], wi);
    }
    float invw = 1.0f / wsum;
    wr *= invw; wi *= invw;
    float mag = sqrtf(wr * wr + wi * wi);
    float scale = fmaxf(mag + mod_bias[f], 0.0f) / (mag + 1e-8f);
    gr[f] = wr * scale;
    gi[f] = wi * scale;
  }
  __syncthreads();
  float k_r[5], k_i[5];
#pragma unroll
  for (int j = 0; j < 5; ++j) { k_r[j] = kr5[j]; k_i[j] = ki5[j]; }
  for (int f = tid; f < NFREQ; f += 256) {
    float cr = 0.f, ci = 0.f;
#pragma unroll
    for (int j = 0; j < 5; ++j) {
      int idx = f + j - 2;
      if (idx < 0) idx += NFREQ;
      else if (idx >= NFREQ) idx -= NFREQ;
      float a = gr[idx], bb = gi[idx];
      cr = fmaf(k_r[j], a, cr); cr = fmaf(-k_i[j], bb, cr);
      ci = fmaf(k_r[j], bb, ci); ci = fmaf(k_i[j], a, ci);
    }
    gate_out[((size_t)bh * NFREQ + f) * 2 + 0] = cr;
    gate_out[((size_t)bh * NFREQ + f) * 2 + 1] = ci;
  }
}

// ---------------- k_time = irfft(gate, n=2048), split bf16 out ----------------
__global__ __launch_bounds__(256) void ktime_kernel(
    const float* __restrict__ gate_out, u16t* __restrict__ kth, u16t* __restrict__ ktl) {
  int bh = blockIdx.x, tq = blockIdx.y;
  int tid = threadIdx.x;
  __shared__ float cr[NFREQ], ci[NFREQ];
  __shared__ float ct[NSEQ], st[NSEQ];
  for (int f = tid; f < NFREQ; f += 256) {
    cr[f] = gate_out[((size_t)bh * NFREQ + f) * 2 + 0];
    ci[f] = gate_out[((size_t)bh * NFREQ + f) * 2 + 1];
  }
  const float w0 = 6.283185307179586476925f / 2048.0f;
  for (int m = tid; m < NSEQ; m += 256) {
    float th = w0 * (float)m;
    ct[m] = cosf(th);
    st[m] = sinf(th);
  }
  __syncthreads();
  int t = tq * 256 + tid;
  float acc0 = cr[0] + cr[1024] * ((t & 1) ? -1.0f : 1.0f);
  float acc2 = 0.f;
  for (int f = 1; f < 1024; ++f) {
    int m = (f * t) & 2047;
    acc2 = fmaf(cr[f], ct[m], acc2);
    acc2 = fmaf(-ci[f], st[m], acc2);
  }
  float val = (acc0 + 2.0f * acc2) * (1.0f / 2048.0f);
  u16t h = bf16_rtn(val);
  kth[(size_t)bh * NSEQ + t] = h;
  ktl[(size_t)bh * NSEQ + t] = bf16_rtn(val - bf16f(h));
}

extern "C" void kernel_launch(void* const* d_in, const int* in_sizes, int n_in,
                              void* d_out, int out_size, void* d_ws, size_t ws_size,
                              hipStream_t stream) {
  const float* x        = (const float*)d_in[0];
  const float* Wv       = (const float*)d_in[1];
  const float* bv       = (const float*)d_in[2];
  const float* Wp1      = (const float*)d_in[3];
  const float* bp1      = (const float*)d_in[4];
  const float* Wp2      = (const float*)d_in[5];
  const float* bp2      = (const float*)d_in[6];
  const float* Wg1      = (const float*)d_in[7];
  const float* bg1      = (const float*)d_in[8];
  const float* Wg2      = (const float*)d_in[9];
  const float* bg2      = (const float*)d_in[10];
  const float* mod_bias = (const float*)d_in[11];
  const float* ckr      = (const float*)d_in[12];
  const float* cki      = (const float*)d_in[13];
  const float* Wo       = (const float*)d_in[14];
  const float* bo       = (const float*)d_in[15];

  const int M = NBATCH * NSEQ;          // 8192
  const size_t MD = (size_t)M * DMOD;   // 8M elems

  // ws layout (~37.4 MB):
  u16t* x_hi = (u16t*)d_ws;             // 16 MB ; later reused as y_hi
  u16t* x_lo = x_hi + MD;               // 16 MB ; later reused as y_lo
  u16t* y_hi = x_hi;
  u16t* y_lo = x_lo;
  u16t* WT_h = (u16t*)((char*)d_ws + (size_t)32 * 1024 * 1024);  // 2 MB (max N=1024)
  u16t* WT_l = WT_h + (size_t)1024 * 1024;                        // 2 MB
  float* smallf = (float*)((char*)d_ws + (size_t)36 * 1024 * 1024);
  float* s       = smallf;              // 8192
  float* bstats  = s + 8192;            // 8
  float* gpart   = bstats + 8;          // 65536
  float* g       = gpart + 65536;       // 4096
  float* anchors = g + 4096;            // 4096
  float* gateb   = anchors + 4096;      // 131200
  u16t*  kt_h    = (u16t*)(gateb + 131200);  // 131072 shorts
  u16t*  kt_l    = kt_h + 131072;

  // d_out staging: h1 (8 MB fp32) then v split (16+16 MB bf16), finally fp32 output
  float* h1  = (float*)d_out;
  u16t* v_hi = (u16t*)d_out;
  u16t* v_lo = v_hi + MD;
  float* out = (float*)d_out;

  dim3 blk(256);

  // 0. split x -> bf16 hi/lo
  split_kernel<<<dim3(2048), blk, 0, stream>>>(x, x_hi, x_lo, (int)(MD / 8));
  // 1. Wp1^T split; GEMM2: h1 = gelu(x @ Wp1 + bp1)  (h1 in d_out)
  tsplit_kernel<<<dim3(256 / 32, 1024 / 32), blk, 0, stream>>>(Wp1, WT_h, WT_l, 1024, 256);
  mfma_gemm<true, 0><<<dim3(256 / 128, M / 128), blk, 0, stream>>>(
      x_hi, x_lo, WT_h, WT_l, bp1, h1, (u16t*)nullptr, (u16t*)nullptr, 256, 1024);
  // 2. scores + softmax + pooled g
  score_kernel<<<dim3(M / 4), blk, 0, stream>>>(h1, Wp2, bp2, s);
  softmax_stats_kernel<<<dim3(NBATCH), blk, 0, stream>>>(s, bstats);
  pool_partial_kernel<<<dim3(16, NBATCH), blk, 0, stream>>>(x, s, bstats, gpart);
  pool_reduce_kernel<<<dim3(NBATCH), blk, 0, stream>>>(gpart, g);
  // 3. gate path
  gate_mlp_kernel<<<dim3(NBATCH), blk, 0, stream>>>(g, Wg1, bg1, Wg2, bg2, anchors);
  gate_kernel<<<dim3(NBATCH * NHEAD), blk, 0, stream>>>(anchors, mod_bias, ckr, cki, gateb);
  ktime_kernel<<<dim3(NBATCH * NHEAD, NSEQ / 256), blk, 0, stream>>>(gateb, kt_h, kt_l);
  // 4. Wv^T split; GEMM1: v = x @ Wv + bv -> split into d_out (h1 dead)
  tsplit_kernel<<<dim3(1024 / 32, 1024 / 32), blk, 0, stream>>>(Wv, WT_h, WT_l, 1024, 1024);
  mfma_gemm<false, 1><<<dim3(DMOD / 128, M / 128), blk, 0, stream>>>(
      x_hi, x_lo, WT_h, WT_l, bv, (float*)nullptr, v_hi, v_lo, DMOD, 1024);
  // 5. circular conv via MFMA -> y split (overwrites x split; x dead)
  circconv_mfma<<<dim3(NSEQ / 128, NBATCH * NHEAD), blk, 0, stream>>>(
      v_hi, v_lo, kt_h, kt_l, y_hi, y_lo);
  // 6. Wo^T split; GEMM3: out = y @ Wo + bo -> fp32 d_out (v dead)
  tsplit_kernel<<<dim3(1024 / 32, 1024 / 32), blk, 0, stream>>>(Wo, WT_h, WT_l, 1024, 1024);
  mfma_gemm<false, 0><<<dim3(DMOD / 128, M / 128), blk, 0, stream>>>(
      y_hi, y_lo, WT_h, WT_l, bo, out, (u16t*)nullptr, (u16t*)nullptr, DMOD, 1024);
}

// Round 3
// 463.677 us; speedup vs baseline: 2.3305x; 1.1715x over previous
//
#include <hip/hip_runtime.h>
#include <math.h>

#define NSEQ 2048
#define DMOD 1024
#define NBATCH 4
#define NHEAD 16
#define NFREQ 1025

typedef unsigned short u16t;
typedef __attribute__((ext_vector_type(8))) short short8;
typedef __attribute__((ext_vector_type(4))) float f32x4;

__device__ __forceinline__ float gelu_exact(float x) {
  return 0.5f * x * (1.0f + erff(x * 0.70710678118654752440f));
}
__device__ __forceinline__ u16t bf16_rtn(float x) {
  unsigned u = __float_as_uint(x);
  return (u16t)((u + 0x7FFFu + ((u >> 16) & 1u)) >> 16);
}
__device__ __forceinline__ float bf16f(u16t h) {
  return __uint_as_float(((unsigned)h) << 16);
}
__device__ __forceinline__ void gload_lds16(const u16t* g, u16t* l) {
  __builtin_amdgcn_global_load_lds(
      (const __attribute__((address_space(1))) void*)g,
      (__attribute__((address_space(3))) void*)l, 16, 0, 0);
}

// ---------------- elementwise split fp32 -> bf16 hi/lo ----------------
__global__ __launch_bounds__(256) void split_kernel(const float* __restrict__ in,
    u16t* __restrict__ hi, u16t* __restrict__ lo, int n8) {
  for (int i = blockIdx.x * blockDim.x + threadIdx.x; i < n8; i += gridDim.x * blockDim.x) {
    const float4* p = reinterpret_cast<const float4*>(in + (size_t)i * 8);
    float4 a = p[0], b = p[1];
    float vv[8] = {a.x, a.y, a.z, a.w, b.x, b.y, b.z, b.w};
    alignas(16) u16t th[8];
    alignas(16) u16t tl[8];
#pragma unroll
    for (int e = 0; e < 8; ++e) {
      u16t h = bf16_rtn(vv[e]);
      th[e] = h;
      tl[e] = bf16_rtn(vv[e] - bf16f(h));
    }
    *reinterpret_cast<uint4*>(hi + (size_t)i * 8) = *reinterpret_cast<const uint4*>(th);
    *reinterpret_cast<uint4*>(lo + (size_t)i * 8) = *reinterpret_cast<const uint4*>(tl);
  }
}

// ---------------- transpose + split weights: W[K][N] -> T{h,l}[N][K] ----------------
__global__ __launch_bounds__(256) void tsplit_kernel(const float* __restrict__ W,
    u16t* __restrict__ Th, u16t* __restrict__ Tl, int K, int N) {
  __shared__ float tile[32][33];
  int k0 = blockIdx.y * 32, n0 = blockIdx.x * 32;
  int r = threadIdx.x >> 5, c = threadIdx.x & 31;
#pragma unroll
  for (int i = 0; i < 4; ++i)
    tile[r + 8 * i][c] = W[(size_t)(k0 + r + 8 * i) * N + n0 + c];
  __syncthreads();
#pragma unroll
  for (int i = 0; i < 4; ++i) {
    int rr = r + 8 * i;
    float v = tile[c][rr];
    u16t h = bf16_rtn(v);
    Th[(size_t)(n0 + rr) * K + k0 + c] = h;
    Tl[(size_t)(n0 + rr) * K + k0 + c] = bf16_rtn(v - bf16f(h));
  }
}

// ---------------- split-bf16 MFMA GEMM, m97 structure ----------------
// A: hi/lo bf16 [M][K]; B: transposed hi/lo bf16 [N][K].
// OUTMODE 0: fp32 C [M][N]. OUTMODE 1: split bf16 Ch/Cl [M][N].
// OUTMODE 2: split bf16 transposed v_T layout [b][c][s] (requires N=1024, M=b*2048+s).
template<bool GELU, int OUTMODE>
__global__ __launch_bounds__(256) void mfma_gemm(
    const u16t* __restrict__ Ah_g, const u16t* __restrict__ Al_g,
    const u16t* __restrict__ Bh_g, const u16t* __restrict__ Bl_g,
    const float* __restrict__ bias,
    float* __restrict__ Cf, u16t* __restrict__ Ch, u16t* __restrict__ Cl,
    int N, int K) {
  __shared__ u16t Ahs[128 * 64], Als[128 * 64], Bhs[128 * 64], Bls[128 * 64]; // 64 KB
  const int tid = threadIdx.x;
  const int lane = tid & 63, wave = tid >> 6;
  const int lr = lane & 15, lg = lane >> 4;
  const int wm0 = (wave >> 1) * 64, wn0 = (wave & 1) * 64;
  const int m0 = blockIdx.y * 128, n0 = blockIdx.x * 128;

  f32x4 acc[4][4];
#pragma unroll
  for (int i = 0; i < 4; ++i)
#pragma unroll
    for (int j = 0; j < 4; ++j) acc[i][j] = 0.0f;

  for (int k0 = 0; k0 < K; k0 += 64) {
    // stage 4 arrays via global_load_lds, swizzle on SOURCE (rule #21):
    // physical 16B slot g holds logical k-chunk (g ^ (row&7)).
#pragma unroll
    for (int q = 0; q < 4; ++q) {
      int cid = q * 256 + tid;
      int row = cid >> 3, grp = cid & 7;
      int koff = k0 + ((grp ^ (row & 7)) << 3);
      size_t ea = (size_t)(m0 + row) * K + koff;
      size_t eb = (size_t)(n0 + row) * K + koff;
      int lbase = q * 2048 + wave * 512;      // elems; wave-uniform
      gload_lds16(Ah_g + ea, Ahs + lbase);
      gload_lds16(Al_g + ea, Als + lbase);
      gload_lds16(Bh_g + eb, Bhs + lbase);
      gload_lds16(Bl_g + eb, Bls + lbase);
    }
    __syncthreads();
#pragma unroll
    for (int kf = 0; kf < 2; ++kf) {
      short8 ah[4], al[4];
#pragma unroll
      for (int mi = 0; mi < 4; ++mi) {
        int r_ = wm0 + mi * 16 + lr;
        int g = (kf * 4 + lg) ^ (r_ & 7);
        ah[mi] = *reinterpret_cast<const short8*>(&Ahs[r_ * 64 + g * 8]);
        al[mi] = *reinterpret_cast<const short8*>(&Als[r_ * 64 + g * 8]);
      }
#pragma unroll
      for (int ni = 0; ni < 4; ++ni) {
        int r_ = wn0 + ni * 16 + lr;
        int g = (kf * 4 + lg) ^ (r_ & 7);
        short8 bh8 = *reinterpret_cast<const short8*>(&Bhs[r_ * 64 + g * 8]);
        short8 bl8 = *reinterpret_cast<const short8*>(&Bls[r_ * 64 + g * 8]);
#pragma unroll
        for (int mi = 0; mi < 4; ++mi) {
          acc[mi][ni] = __builtin_amdgcn_mfma_f32_16x16x32_bf16(ah[mi], bh8, acc[mi][ni], 0, 0, 0);
          acc[mi][ni] = __builtin_amdgcn_mfma_f32_16x16x32_bf16(ah[mi], bl8, acc[mi][ni], 0, 0, 0);
          acc[mi][ni] = __builtin_amdgcn_mfma_f32_16x16x32_bf16(al[mi], bh8, acc[mi][ni], 0, 0, 0);
        }
      }
    }
    __syncthreads();
  }
#pragma unroll
  for (int mi = 0; mi < 4; ++mi)
#pragma unroll
    for (int ni = 0; ni < 4; ++ni) {
      int col = n0 + wn0 + ni * 16 + lr;
      float bv = bias[col];
      f32x4 a = acc[mi][ni];
      if (OUTMODE == 2) {
        int mbase = m0 + wm0 + mi * 16 + lg * 4;
        int b = mbase >> 11, s = mbase & 2047;
        alignas(8) u16t hv[4], lv[4];
#pragma unroll
        for (int r = 0; r < 4; ++r) {
          float val = a[r] + bv;
          u16t h = bf16_rtn(val);
          hv[r] = h;
          lv[r] = bf16_rtn(val - bf16f(h));
        }
        size_t o = (size_t)b * (DMOD * NSEQ) + (size_t)col * NSEQ + s;
        *reinterpret_cast<ushort4*>(&Ch[o]) = *reinterpret_cast<const ushort4*>(hv);
        *reinterpret_cast<ushort4*>(&Cl[o]) = *reinterpret_cast<const ushort4*>(lv);
      } else {
#pragma unroll
        for (int r = 0; r < 4; ++r) {
          int row = m0 + wm0 + mi * 16 + lg * 4 + r;
          float val = a[r] + bv;
          if (GELU) val = gelu_exact(val);
          if (OUTMODE == 0) {
            Cf[(size_t)row * N + col] = val;
          } else {
            u16t h = bf16_rtn(val);
            Ch[(size_t)row * N + col] = h;
            Cl[(size_t)row * N + col] = bf16_rtn(val - bf16f(h));
          }
        }
      }
    }
}

// ---------------- circular conv via MFMA ----------------
// y[b,t,c] = sum_s kt[b,h(c),(t-s)&2047] * v[b,s,c]
// v given transposed v_T[b][c][s]; kt given as 8 reversed shifted copies
// kt8[r][i] = kt[-(i+r) mod 2048] so A-frags are single aligned b128 global loads.
__global__ __launch_bounds__(256) void circconv_mfma(
    const u16t* __restrict__ vT_h, const u16t* __restrict__ vT_l,
    const u16t* __restrict__ kt8_h, const u16t* __restrict__ kt8_l,
    u16t* __restrict__ y_hi, u16t* __restrict__ y_lo) {
  __shared__ u16t Bhs[64 * 64], Bls[64 * 64];   // 16 KB
  const int tid = threadIdx.x;
  const int lane = tid & 63, wave = tid >> 6;
  const int lr = lane & 15, lg = lane >> 4;
  const int t0 = blockIdx.x * 256;
  const int bh = blockIdx.y;
  const int b = bh >> 4;
  const int c0 = (bh & 15) * 64;
  const u16t* k8h = kt8_h + (size_t)bh * (8 * 2048);
  const u16t* k8l = kt8_l + (size_t)bh * (8 * 2048);
  const size_t vbase = (size_t)b * (DMOD * NSEQ);
  const int twave = t0 + wave * 64;

  f32x4 acc[4][4];
#pragma unroll
  for (int i = 0; i < 4; ++i)
#pragma unroll
    for (int j = 0; j < 4; ++j) acc[i][j] = 0.0f;

  for (int s0 = 0; s0 < NSEQ; s0 += 64) {
#pragma unroll
    for (int q = 0; q < 2; ++q) {
      int cid = q * 256 + tid;
      int row = cid >> 3, grp = cid & 7;
      size_t src = vbase + (size_t)(c0 + row) * NSEQ + s0 + ((grp ^ (row & 7)) << 3);
      int lbase = q * 2048 + wave * 512;
      gload_lds16(vT_h + src, Bhs + lbase);
      gload_lds16(vT_l + src, Bls + lbase);
    }
    __syncthreads();
#pragma unroll
    for (int kf = 0; kf < 2; ++kf) {
      short8 ah[4], al[4];
#pragma unroll
      for (int mi = 0; mi < 4; ++mi) {
        int tg = twave + mi * 16 + lr;
        int E = (s0 + kf * 32 + lg * 8 - tg) & 2047;
        int r = E & 7;
        int off = r * 2048 + (E - r);
        ah[mi] = *reinterpret_cast<const short8*>(&k8h[off]);
        al[mi] = *reinterpret_cast<const short8*>(&k8l[off]);
      }
#pragma unroll
      for (int ni = 0; ni < 4; ++ni) {
        int row = ni * 16 + lr;
        int g = (kf * 4 + lg) ^ (row & 7);
        short8 bh8 = *reinterpret_cast<const short8*>(&Bhs[row * 64 + g * 8]);
        short8 bl8 = *reinterpret_cast<const short8*>(&Bls[row * 64 + g * 8]);
#pragma unroll
        for (int mi = 0; mi < 4; ++mi) {
          acc[mi][ni] = __builtin_amdgcn_mfma_f32_16x16x32_bf16(ah[mi], bh8, acc[mi][ni], 0, 0, 0);
          acc[mi][ni] = __builtin_amdgcn_mfma_f32_16x16x32_bf16(ah[mi], bl8, acc[mi][ni], 0, 0, 0);
          acc[mi][ni] = __builtin_amdgcn_mfma_f32_16x16x32_bf16(al[mi], bh8, acc[mi][ni], 0, 0, 0);
        }
      }
    }
    __syncthreads();
  }
#pragma unroll
  for (int mi = 0; mi < 4; ++mi)
#pragma unroll
    for (int ni = 0; ni < 4; ++ni) {
      int c = c0 + ni * 16 + lr;
#pragma unroll
      for (int r = 0; r < 4; ++r) {
        int t = twave + mi * 16 + lg * 4 + r;
        size_t o = ((size_t)b * NSEQ + t) * DMOD + c;
        float val = acc[mi][ni][r];
        u16t hh = bf16_rtn(val);
        y_hi[o] = hh;
        y_lo[o] = bf16_rtn(val - bf16f(hh));
      }
    }
}

// ---------------- scores s = h1 @ Wp2 + bp2 (K=256) ----------------
__global__ __launch_bounds__(256) void score_kernel(
    const float* __restrict__ h1, const float* __restrict__ Wp2,
    const float* __restrict__ bp2, float* __restrict__ s) {
  int tid = threadIdx.x;
  int lane = tid & 63, w = tid >> 6;
  int row = blockIdx.x * 4 + w;
  float acc = 0.f;
#pragma unroll
  for (int q = 0; q < 4; ++q) {
    int k = lane + 64 * q;
    acc = fmaf(h1[(size_t)row * 256 + k], Wp2[k], acc);
  }
#pragma unroll
  for (int off = 32; off; off >>= 1) acc += __shfl_down(acc, off);
  if (lane == 0) s[row] = acc + bp2[0];
}

// ---------------- per-batch softmax stats ----------------
__global__ __launch_bounds__(256) void softmax_stats_kernel(
    const float* __restrict__ s, float* __restrict__ bstats) {
  int b = blockIdx.x, tid = threadIdx.x;
  __shared__ float red[256];
  float m = -1e30f;
  for (int n = tid; n < NSEQ; n += 256) m = fmaxf(m, s[b * NSEQ + n]);
  red[tid] = m; __syncthreads();
  for (int o = 128; o; o >>= 1) { if (tid < o) red[tid] = fmaxf(red[tid], red[tid + o]); __syncthreads(); }
  float bm = red[0]; __syncthreads();
  float sum = 0.f;
  for (int n = tid; n < NSEQ; n += 256) sum += expf(s[b * NSEQ + n] - bm);
  red[tid] = sum; __syncthreads();
  for (int o = 128; o; o >>= 1) { if (tid < o) red[tid] += red[tid + o]; __syncthreads(); }
  if (tid == 0) { bstats[b * 2] = bm; bstats[b * 2 + 1] = red[0]; }
}

// ---------------- pooled g ----------------
__global__ __launch_bounds__(256) void pool_partial_kernel(
    const float* __restrict__ x, const float* __restrict__ s,
    const float* __restrict__ bstats, float* __restrict__ gpart) {
  int chunk = blockIdx.x, b = blockIdx.y;
  int tid = threadIdx.x;
  __shared__ float wsh[128];
  float bm = bstats[b * 2], inv = 1.0f / bstats[b * 2 + 1];
  int n0 = chunk * 128;
  if (tid < 128) wsh[tid] = expf(s[b * NSEQ + n0 + tid] - bm) * inv;
  __syncthreads();
  float acc[4] = {};
  for (int n = 0; n < 128; ++n) {
    float wn = wsh[n];
    const float* xr = &x[((size_t)b * NSEQ + n0 + n) * DMOD];
#pragma unroll
    for (int q = 0; q < 4; ++q) acc[q] = fmaf(wn, xr[tid + 256 * q], acc[q]);
  }
  float* gp = &gpart[((size_t)b * 16 + chunk) * DMOD];
#pragma unroll
  for (int q = 0; q < 4; ++q) gp[tid + 256 * q] = acc[q];
}

__global__ __launch_bounds__(256) void pool_reduce_kernel(
    const float* __restrict__ gpart, float* __restrict__ g) {
  int b = blockIdx.x, tid = threadIdx.x;
  for (int d = tid; d < DMOD; d += 256) {
    float acc = 0.f;
    for (int c = 0; c < 16; ++c) acc += gpart[((size_t)b * 16 + c) * DMOD + d];
    g[b * DMOD + d] = acc;
  }
}

// ---------------- gate MLP -> anchors ----------------
__global__ __launch_bounds__(256) void gate_mlp_kernel(
    const float* __restrict__ g, const float* __restrict__ Wg1,
    const float* __restrict__ bg1, const float* __restrict__ Wg2,
    const float* __restrict__ bg2, float* __restrict__ anchors) {
  int b = blockIdx.x, tid = threadIdx.x;
  __shared__ float gs[1024];
  __shared__ float hs[256];
  for (int d = tid; d < 1024; d += 256) gs[d] = g[b * 1024 + d];
  __syncthreads();
  float acc = bg1[tid];
  for (int i = 0; i < 1024; ++i) acc = fmaf(gs[i], Wg1[i * 256 + tid], acc);
  hs[tid] = gelu_exact(acc);
  __syncthreads();
#pragma unroll
  for (int q = 0; q < 4; ++q) {
    int c = tid + 256 * q;
    float a2 = bg2[c];
    for (int i = 0; i < 256; ++i) a2 = fmaf(hs[i], Wg2[i * 1024 + c], a2);
    anchors[b * 1024 + c] = a2;
  }
}

// ---------------- cubic resize + modReLU + complex conv ----------------
__device__ __forceinline__ float keys_cubic(float x) {
  if (x >= 2.0f) return 0.0f;
  if (x >= 1.0f) return ((-0.5f * x + 2.5f) * x - 4.0f) * x + 2.0f;
  return ((1.5f * x - 2.5f) * x) * x + 1.0f;
}

__global__ __launch_bounds__(256) void gate_kernel(
    const float* __restrict__ anchors, const float* __restrict__ mod_bias,
    const float* __restrict__ kr5, const float* __restrict__ ki5,
    float* __restrict__ gate_out) {
  int bh = blockIdx.x;
  int tid = threadIdx.x;
  __shared__ float ar_[32], ai_[32];
  __shared__ float gr[NFREQ], gi[NFREQ];
  if (tid < 32) {
    ar_[tid] = anchors[bh * 64 + tid * 2 + 0];
    ai_[tid] = anchors[bh * 64 + tid * 2 + 1];
  }
  __syncthreads();
  const float inv_scale = 32.0f / 1025.0f;
  for (int f = tid; f < NFREQ; f += 256) {
    float c = (f + 0.5f) * inv_scale - 0.5f;
    int j0 = (int)floorf(c) - 1;
    float wr = 0.f, wi = 0.f, wsum = 0.f;
#pragma unroll
    for (int u = 0; u < 4; ++u) {
      int j = j0 + u;
      if (j < 0 || j > 31) continue;
      float w = keys_cubic(fabsf(c - (float)j));
      wsum += w;
      wr = fmaf(w, ar_[j], wr);
      wi = fmaf(w, ai_[j], wi);
    }
    float invw = 1.0f / wsum;
    wr *= invw; wi *= invw;
    float mag = sqrtf(wr * wr + wi * wi);
    float scale = fmaxf(mag + mod_bias[f], 0.0f) / (mag + 1e-8f);
    gr[f] = wr * scale;
    gi[f] = wi * scale;
  }
  __syncthreads();
  float k_r[5], k_i[5];
#pragma unroll
  for (int j = 0; j < 5; ++j) { k_r[j] = kr5[j]; k_i[j] = ki5[j]; }
  for (int f = tid; f < NFREQ; f += 256) {
    float cr = 0.f, ci = 0.f;
#pragma unroll
    for (int j = 0; j < 5; ++j) {
      int idx = f + j - 2;
      if (idx < 0) idx += NFREQ;
      else if (idx >= NFREQ) idx -= NFREQ;
      float a = gr[idx], bb = gi[idx];
      cr = fmaf(k_r[j], a, cr); cr = fmaf(-k_i[j], bb, cr);
      ci = fmaf(k_r[j], bb, ci); ci = fmaf(k_i[j], a, ci);
    }
    gate_out[((size_t)bh * NFREQ + f) * 2 + 0] = cr;
    gate_out[((size_t)bh * NFREQ + f) * 2 + 1] = ci;
  }
}

// ---------------- k_time = irfft(gate, n=2048); write 8 reversed shifted copies ----------------
__global__ __launch_bounds__(256) void ktime_kernel(
    const float* __restrict__ gate_out, u16t* __restrict__ kt8h, u16t* __restrict__ kt8l) {
  int bh = blockIdx.x, tq = blockIdx.y;
  int tid = threadIdx.x;
  __shared__ float cr[NFREQ], ci[NFREQ];
  __shared__ float ct[NSEQ], st[NSEQ];
  for (int f = tid; f < NFREQ; f += 256) {
    cr[f] = gate_out[((size_t)bh * NFREQ + f) * 2 + 0];
    ci[f] = gate_out[((size_t)bh * NFREQ + f) * 2 + 1];
  }
  const float w0 = 6.283185307179586476925f / 2048.0f;
  for (int m = tid; m < NSEQ; m += 256) {
    float th = w0 * (float)m;
    ct[m] = cosf(th);
    st[m] = sinf(th);
  }
  __syncthreads();
  int t = tq * 256 + tid;
  float acc0 = cr[0] + cr[1024] * ((t & 1) ? -1.0f : 1.0f);
  float acc2 = 0.f;
  for (int f = 1; f < 1024; ++f) {
    int m = (f * t) & 2047;
    acc2 = fmaf(cr[f], ct[m], acc2);
    acc2 = fmaf(-ci[f], st[m], acc2);
  }
  float val = (acc0 + 2.0f * acc2) * (1.0f / 2048.0f);
  u16t h = bf16_rtn(val);
  u16t l = bf16_rtn(val - bf16f(h));
  size_t base = (size_t)bh * (8 * 2048);
#pragma unroll
  for (int r = 0; r < 8; ++r) {
    int p = (-t - r) & 2047;
    kt8h[base + r * 2048 + p] = h;
    kt8l[base + r * 2048 + p] = l;
  }
}

extern "C" void kernel_launch(void* const* d_in, const int* in_sizes, int n_in,
                              void* d_out, int out_size, void* d_ws, size_t ws_size,
                              hipStream_t stream) {
  const float* x        = (const float*)d_in[0];
  const float* Wv       = (const float*)d_in[1];
  const float* bv       = (const float*)d_in[2];
  const float* Wp1      = (const float*)d_in[3];
  const float* bp1      = (const float*)d_in[4];
  const float* Wp2      = (const float*)d_in[5];
  const float* bp2      = (const float*)d_in[6];
  const float* Wg1      = (const float*)d_in[7];
  const float* bg1      = (const float*)d_in[8];
  const float* Wg2      = (const float*)d_in[9];
  const float* bg2      = (const float*)d_in[10];
  const float* mod_bias = (const float*)d_in[11];
  const float* ckr      = (const float*)d_in[12];
  const float* cki      = (const float*)d_in[13];
  const float* Wo       = (const float*)d_in[14];
  const float* bo       = (const float*)d_in[15];

  const int M = NBATCH * NSEQ;          // 8192
  const size_t MD = (size_t)M * DMOD;   // 8M elems

  // ws layout (~36.9 MB):
  u16t* x_hi = (u16t*)d_ws;             // 16 MB ; later reused as y_hi
  u16t* x_lo = x_hi + MD;               // 16 MB ; later reused as y_lo
  u16t* y_hi = x_hi;
  u16t* y_lo = x_lo;
  u16t* WT_h = (u16t*)((char*)d_ws + (size_t)32 * 1024 * 1024);  // 2 MB
  u16t* WT_l = WT_h + (size_t)1024 * 1024;                        // 2 MB
  u16t* kt8_h = WT_h;                   // alias: 64*8*2048*2B = 2 MB (WT(Wv) dead)
  u16t* kt8_l = WT_l;
  float* smallf = (float*)((char*)d_ws + (size_t)36 * 1024 * 1024);
  float* s       = smallf;              // 8192
  float* bstats  = s + 8192;            // 8
  float* gpart   = bstats + 8;          // 65536
  float* g       = gpart + 65536;       // 4096
  float* anchors = g + 4096;            // 4096
  float* gateb   = anchors + 4096;      // 131200

  // d_out staging: h1 (8 MB fp32), then v_T split (16+16 MB bf16), finally fp32 out
  float* h1   = (float*)d_out;
  u16t* vT_h  = (u16t*)d_out;
  u16t* vT_l  = vT_h + MD;
  float* out  = (float*)d_out;

  dim3 blk(256);

  // 0. split x -> bf16 hi/lo
  split_kernel<<<dim3(2048), blk, 0, stream>>>(x, x_hi, x_lo, (int)(MD / 8));
  // 1. Wp1^T split; GEMM2: h1 = gelu(x @ Wp1 + bp1)
  tsplit_kernel<<<dim3(256 / 32, 1024 / 32), blk, 0, stream>>>(Wp1, WT_h, WT_l, 1024, 256);
  mfma_gemm<true, 0><<<dim3(256 / 128, M / 128), blk, 0, stream>>>(
      x_hi, x_lo, WT_h, WT_l, bp1, h1, (u16t*)nullptr, (u16t*)nullptr, 256, 1024);
  // 2. scores + softmax + pooled g
  score_kernel<<<dim3(M / 4), blk, 0, stream>>>(h1, Wp2, bp2, s);
  softmax_stats_kernel<<<dim3(NBATCH), blk, 0, stream>>>(s, bstats);
  pool_partial_kernel<<<dim3(16, NBATCH), blk, 0, stream>>>(x, s, bstats, gpart);
  pool_reduce_kernel<<<dim3(NBATCH), blk, 0, stream>>>(gpart, g);
  // 3. gate path
  gate_mlp_kernel<<<dim3(NBATCH), blk, 0, stream>>>(g, Wg1, bg1, Wg2, bg2, anchors);
  gate_kernel<<<dim3(NBATCH * NHEAD), blk, 0, stream>>>(anchors, mod_bias, ckr, cki, gateb);
  // 4. Wv^T split; GEMM1: v = x @ Wv + bv -> transposed split v_T in d_out (h1 dead)
  tsplit_kernel<<<dim3(1024 / 32, 1024 / 32), blk, 0, stream>>>(Wv, WT_h, WT_l, 1024, 1024);
  mfma_gemm<false, 2><<<dim3(DMOD / 128, M / 128), blk, 0, stream>>>(
      x_hi, x_lo, WT_h, WT_l, bv, (float*)nullptr, vT_h, vT_l, DMOD, 1024);
  // 5. ktime -> kt8 copies (overwrites WT; Wv WT dead after GEMM1)
  ktime_kernel<<<dim3(NBATCH * NHEAD, NSEQ / 256), blk, 0, stream>>>(gateb, kt8_h, kt8_l);
  // 6. circular conv -> y split (overwrites x split; x dead)
  circconv_mfma<<<dim3(NSEQ / 256, NBATCH * NHEAD), blk, 0, stream>>>(
      vT_h, vT_l, kt8_h, kt8_l, y_hi, y_lo);
  // 7. Wo^T split (overwrites kt8; dead); GEMM3: out = y @ Wo + bo
  tsplit_kernel<<<dim3(1024 / 32, 1024 / 32), blk, 0, stream>>>(Wo, WT_h, WT_l, 1024, 1024);
  mfma_gemm<false, 0><<<dim3(DMOD / 128, M / 128), blk, 0, stream>>>(
      y_hi, y_lo, WT_h, WT_l, bo, out, (u16t*)nullptr, (u16t*)nullptr, DMOD, 1024);
}

// Round 4
// 325.895 us; speedup vs baseline: 3.3158x; 1.4228x over previous
//
#include <hip/hip_runtime.h>
#include <math.h>

#define NSEQ 2048
#define DMOD 1024
#define NBATCH 4
#define NHEAD 16
#define NFREQ 1025

typedef unsigned short u16t;
typedef __attribute__((ext_vector_type(8))) short short8;
typedef __attribute__((ext_vector_type(4))) float f32x4;

__device__ __forceinline__ float gelu_exact(float x) {
  return 0.5f * x * (1.0f + erff(x * 0.70710678118654752440f));
}
__device__ __forceinline__ u16t bf16_rtn(float x) {
  unsigned u = __float_as_uint(x);
  return (u16t)((u + 0x7FFFu + ((u >> 16) & 1u)) >> 16);
}
__device__ __forceinline__ float bf16f(u16t h) {
  return __uint_as_float(((unsigned)h) << 16);
}
__device__ __forceinline__ void gload_lds16(const u16t* g, u16t* l) {
  __builtin_amdgcn_global_load_lds(
      (const __attribute__((address_space(1))) void*)g,
      (__attribute__((address_space(3))) void*)l, 16, 0, 0);
}

// ---------------- elementwise split fp32 -> bf16 hi/lo ----------------
__global__ __launch_bounds__(256) void split_kernel(const float* __restrict__ in,
    u16t* __restrict__ hi, u16t* __restrict__ lo, int n8) {
  for (int i = blockIdx.x * blockDim.x + threadIdx.x; i < n8; i += gridDim.x * blockDim.x) {
    const float4* p = reinterpret_cast<const float4*>(in + (size_t)i * 8);
    float4 a = p[0], b = p[1];
    float vv[8] = {a.x, a.y, a.z, a.w, b.x, b.y, b.z, b.w};
    alignas(16) u16t th[8];
    alignas(16) u16t tl[8];
#pragma unroll
    for (int e = 0; e < 8; ++e) {
      u16t h = bf16_rtn(vv[e]);
      th[e] = h;
      tl[e] = bf16_rtn(vv[e] - bf16f(h));
    }
    *reinterpret_cast<uint4*>(hi + (size_t)i * 8) = *reinterpret_cast<const uint4*>(th);
    *reinterpret_cast<uint4*>(lo + (size_t)i * 8) = *reinterpret_cast<const uint4*>(tl);
  }
}

// ---------------- transpose + split weights: W[K][N] -> T{h,l}[N][K] ----------------
__global__ __launch_bounds__(256) void tsplit_kernel(const float* __restrict__ W,
    u16t* __restrict__ Th, u16t* __restrict__ Tl, int K, int N) {
  __shared__ float tile[32][33];
  int k0 = blockIdx.y * 32, n0 = blockIdx.x * 32;
  int r = threadIdx.x >> 5, c = threadIdx.x & 31;
#pragma unroll
  for (int i = 0; i < 4; ++i)
    tile[r + 8 * i][c] = W[(size_t)(k0 + r + 8 * i) * N + n0 + c];
  __syncthreads();
#pragma unroll
  for (int i = 0; i < 4; ++i) {
    int rr = r + 8 * i;
    float v = tile[c][rr];
    u16t h = bf16_rtn(v);
    Th[(size_t)(n0 + rr) * K + k0 + c] = h;
    Tl[(size_t)(n0 + rr) * K + k0 + c] = bf16_rtn(v - bf16f(h));
  }
}

// ---------------- split-bf16 MFMA GEMM ----------------
// A: hi/lo bf16 [M][K]; B: transposed hi/lo bf16 [N][K].
// OUTMODE 0: fp32 C [M][N].
// OUTMODE 2: fp32 transposed v_T layout [b][c][s] (requires N=1024, m = b*2048+s).
template<bool GELU, int OUTMODE>
__global__ __launch_bounds__(256) void mfma_gemm(
    const u16t* __restrict__ Ah_g, const u16t* __restrict__ Al_g,
    const u16t* __restrict__ Bh_g, const u16t* __restrict__ Bl_g,
    const float* __restrict__ bias,
    float* __restrict__ Cf,
    int N, int K) {
  __shared__ u16t Ahs[128 * 64], Als[128 * 64], Bhs[128 * 64], Bls[128 * 64]; // 64 KB
  const int tid = threadIdx.x;
  const int lane = tid & 63, wave = tid >> 6;
  const int lr = lane & 15, lg = lane >> 4;
  const int wm0 = (wave >> 1) * 64, wn0 = (wave & 1) * 64;
  const int m0 = blockIdx.y * 128, n0 = blockIdx.x * 128;

  f32x4 acc[4][4];
#pragma unroll
  for (int i = 0; i < 4; ++i)
#pragma unroll
    for (int j = 0; j < 4; ++j) acc[i][j] = 0.0f;

  for (int k0 = 0; k0 < K; k0 += 64) {
#pragma unroll
    for (int q = 0; q < 4; ++q) {
      int cid = q * 256 + tid;
      int row = cid >> 3, grp = cid & 7;
      int koff = k0 + ((grp ^ (row & 7)) << 3);
      size_t ea = (size_t)(m0 + row) * K + koff;
      size_t eb = (size_t)(n0 + row) * K + koff;
      int lbase = q * 2048 + wave * 512;
      gload_lds16(Ah_g + ea, Ahs + lbase);
      gload_lds16(Al_g + ea, Als + lbase);
      gload_lds16(Bh_g + eb, Bhs + lbase);
      gload_lds16(Bl_g + eb, Bls + lbase);
    }
    __syncthreads();
#pragma unroll
    for (int kf = 0; kf < 2; ++kf) {
      short8 ah[4], al[4];
#pragma unroll
      for (int mi = 0; mi < 4; ++mi) {
        int r_ = wm0 + mi * 16 + lr;
        int g = (kf * 4 + lg) ^ (r_ & 7);
        ah[mi] = *reinterpret_cast<const short8*>(&Ahs[r_ * 64 + g * 8]);
        al[mi] = *reinterpret_cast<const short8*>(&Als[r_ * 64 + g * 8]);
      }
#pragma unroll
      for (int ni = 0; ni < 4; ++ni) {
        int r_ = wn0 + ni * 16 + lr;
        int g = (kf * 4 + lg) ^ (r_ & 7);
        short8 bh8 = *reinterpret_cast<const short8*>(&Bhs[r_ * 64 + g * 8]);
        short8 bl8 = *reinterpret_cast<const short8*>(&Bls[r_ * 64 + g * 8]);
#pragma unroll
        for (int mi = 0; mi < 4; ++mi) {
          acc[mi][ni] = __builtin_amdgcn_mfma_f32_16x16x32_bf16(ah[mi], bh8, acc[mi][ni], 0, 0, 0);
          acc[mi][ni] = __builtin_amdgcn_mfma_f32_16x16x32_bf16(ah[mi], bl8, acc[mi][ni], 0, 0, 0);
          acc[mi][ni] = __builtin_amdgcn_mfma_f32_16x16x32_bf16(al[mi], bh8, acc[mi][ni], 0, 0, 0);
        }
      }
    }
    __syncthreads();
  }
#pragma unroll
  for (int mi = 0; mi < 4; ++mi)
#pragma unroll
    for (int ni = 0; ni < 4; ++ni) {
      int col = n0 + wn0 + ni * 16 + lr;
      float bv = bias[col];
      f32x4 a = acc[mi][ni];
      if (OUTMODE == 2) {
        int mbase = m0 + wm0 + mi * 16 + lg * 4;
        int b = mbase >> 11, ss = mbase & 2047;
        float4 o4;
        o4.x = a[0] + bv; o4.y = a[1] + bv; o4.z = a[2] + bv; o4.w = a[3] + bv;
        *reinterpret_cast<float4*>(Cf + (size_t)b * (DMOD * NSEQ) + (size_t)col * NSEQ + ss) = o4;
      } else {
#pragma unroll
        for (int r = 0; r < 4; ++r) {
          int row = m0 + wm0 + mi * 16 + lg * 4 + r;
          float val = a[r] + bv;
          if (GELU) val = gelu_exact(val);
          Cf[(size_t)row * N + col] = val;
        }
      }
    }
}

// ---------------- fused rFFT * gate * irFFT, in place on vT[b][c][s] ----------------
// One wave per column; 1024-pt complex FFT of packed real pairs; DIF fwd (bit-rev
// out) + untangle*gate*retangle at bit-rev positions + DIT inv (bit-rev in).
__global__ __launch_bounds__(256) void conv_fft_kernel(
    float* __restrict__ vio, const float* __restrict__ gateb) {
  __shared__ float2 Z[4][1024];    // 32 KB
  __shared__ float2 TW[512];       // e^{-2pi i m/1024}
  __shared__ float2 TWH[512];      // e^{-pi i k/1024}
  const int tid = threadIdx.x;
  const int lane = tid & 63, wave = tid >> 6;
  const int c0 = blockIdx.x * 4;
  const int b = blockIdx.y;
  const int bh = b * NHEAD + (c0 >> 6);
  const float* gate_bh = gateb + (size_t)bh * NFREQ * 2;

#pragma unroll
  for (int q = 0; q < 2; ++q) {
    int m = q * 256 + tid;
    float si, co;
    sincosf(-3.14159265358979323846f * (float)m * (1.0f / 512.0f), &si, &co);
    TW[m] = make_float2(co, si);
    float si2, co2;
    sincosf(-3.14159265358979323846f * (float)m * (1.0f / 1024.0f), &si2, &co2);
    TWH[m] = make_float2(co2, si2);
  }
  __syncthreads();

  float2* Zc = Z[wave];
  float* col = vio + ((size_t)b * DMOD + (c0 + wave)) * NSEQ;

  // load packed z[n] = v[2n] + i v[2n+1]
#pragma unroll
  for (int q = 0; q < 8; ++q) {
    int i4 = q * 64 + lane;
    float4 w4 = *reinterpret_cast<const float4*>(col + i4 * 4);
    *reinterpret_cast<float4*>(&Zc[2 * i4]) = w4;
  }
  asm volatile("s_waitcnt lgkmcnt(0)" ::: "memory");

  // forward DIF, 10 stages
  for (int lh = 9; lh >= 0; --lh) {
    int h = 1 << lh;
#pragma unroll
    for (int q = 0; q < 8; ++q) {
      int m = q * 64 + lane;
      int j = m & (h - 1);
      int base = ((m >> lh) << (lh + 1)) | j;
      float2 u = Zc[base], v = Zc[base + h];
      float2 tw = TW[j << (9 - lh)];
      float dx = u.x - v.x, dy = u.y - v.y;
      Zc[base] = make_float2(u.x + v.x, u.y + v.y);
      Zc[base + h] = make_float2(dx * tw.x - dy * tw.y, dx * tw.y + dy * tw.x);
    }
    asm volatile("s_waitcnt lgkmcnt(0)" ::: "memory");
  }

  // untangle -> X[k]; Y = X*G/1024; retangle -> W stored bit-reversed
  const float s1 = 1.0f / 1024.0f;
#pragma unroll
  for (int q = 0; q < 8; ++q) {
    int k = q * 64 + lane;
    if (k == 0) {
      float2 Z0 = Zc[0];
      float X0 = Z0.x + Z0.y;
      float XN = Z0.x - Z0.y;
      float2 G0 = *reinterpret_cast<const float2*>(gate_bh + 0);
      float2 GN = *reinterpret_cast<const float2*>(gate_bh + 1024 * 2);
      float y0 = X0 * G0.x * s1;    // irfft uses Re only at DC/Nyquist
      float yN = XN * GN.x * s1;
      Zc[0] = make_float2(0.5f * (y0 + yN), 0.5f * (y0 - yN));
      // k = 512: X = conj(Z[rev(512)=1]); W = conj(Y)
      float2 Zm = Zc[1];
      float2 X5 = make_float2(Zm.x, -Zm.y);
      float2 G5 = *reinterpret_cast<const float2*>(gate_bh + 512 * 2);
      float2 Y5 = make_float2((X5.x * G5.x - X5.y * G5.y) * s1,
                              (X5.x * G5.y + X5.y * G5.x) * s1);
      Zc[1] = make_float2(Y5.x, -Y5.y);
    } else {
      int kq = 1024 - k;
      int rp = __brev((unsigned)k) >> 22;
      int rq = __brev((unsigned)kq) >> 22;
      float2 Zk = Zc[rp], Zq = Zc[rq];
      float Er = 0.5f * (Zk.x + Zq.x), Ei = 0.5f * (Zk.y - Zq.y);
      float Odr = 0.5f * (Zk.y + Zq.y), Odi = -0.5f * (Zk.x - Zq.x);
      float2 t = TWH[k];
      float Pr = Odr * t.x - Odi * t.y, Pi = Odr * t.y + Odi * t.x;
      float2 Xk = make_float2(Er + Pr, Ei + Pi);
      float2 Xq = make_float2(Er - Pr, -(Ei - Pi));
      float2 Gk = *reinterpret_cast<const float2*>(gate_bh + k * 2);
      float2 Gq = *reinterpret_cast<const float2*>(gate_bh + kq * 2);
      float2 Yk = make_float2((Xk.x * Gk.x - Xk.y * Gk.y) * s1,
                              (Xk.x * Gk.y + Xk.y * Gk.x) * s1);
      float2 Yq = make_float2((Xq.x * Gq.x - Xq.y * Gq.y) * s1,
                              (Xq.x * Gq.y + Xq.y * Gq.x) * s1);
      float E2r = 0.5f * (Yk.x + Yq.x), E2i = 0.5f * (Yk.y - Yq.y);
      float D2r = 0.5f * (Yk.x - Yq.x), D2i = 0.5f * (Yk.y + Yq.y);
      // O2 = D2 * conj(TWH[k])
      float O2r = D2r * t.x + D2i * t.y, O2i = D2i * t.x - D2r * t.y;
      Zc[rp] = make_float2(E2r - O2i, E2i + O2r);   // W[k]  = E2 + i*O2
      Zc[rq] = make_float2(E2r + O2i, O2r - E2i);   // W[kq] = conj(E2) + i*conj(O2)
    }
  }
  asm volatile("s_waitcnt lgkmcnt(0)" ::: "memory");

  // inverse DIT, 10 stages (conjugate twiddles), natural-order output
  for (int lh = 0; lh <= 9; ++lh) {
    int h = 1 << lh;
#pragma unroll
    for (int q = 0; q < 8; ++q) {
      int m = q * 64 + lane;
      int j = m & (h - 1);
      int base = ((m >> lh) << (lh + 1)) | j;
      float2 u = Zc[base], v = Zc[base + h];
      float2 tw = TW[j << (9 - lh)];
      float tx = v.x * tw.x + v.y * tw.y, ty = v.y * tw.x - v.x * tw.y;
      Zc[base] = make_float2(u.x + tx, u.y + ty);
      Zc[base + h] = make_float2(u.x - tx, u.y - ty);
    }
    asm volatile("s_waitcnt lgkmcnt(0)" ::: "memory");
  }

  // store y in place: y[2n] = Re z'[n], y[2n+1] = Im z'[n]
#pragma unroll
  for (int q = 0; q < 8; ++q) {
    int i4 = q * 64 + lane;
    float4 w4 = *reinterpret_cast<const float4*>(&Zc[2 * i4]);
    *reinterpret_cast<float4*>(col + i4 * 4) = w4;
  }
}

// ---------------- transpose + split: yT[b][c][t] fp32 -> y{h,l}[b][t][c] bf16 ----------------
__global__ __launch_bounds__(256) void tysplit_kernel(
    const float* __restrict__ yT, u16t* __restrict__ yh, u16t* __restrict__ yl) {
  __shared__ float tile[64][65];
  int t0 = blockIdx.x * 64, c0 = blockIdx.y * 64, b = blockIdx.z;
  int r = threadIdx.x >> 4;
  int cc = (threadIdx.x & 15) * 4;
#pragma unroll
  for (int i = 0; i < 4; ++i) {
    int row = r + 16 * i;
    float4 w = *reinterpret_cast<const float4*>(
        yT + ((size_t)b * DMOD + c0 + row) * NSEQ + t0 + cc);
    tile[row][cc] = w.x; tile[row][cc + 1] = w.y;
    tile[row][cc + 2] = w.z; tile[row][cc + 3] = w.w;
  }
  __syncthreads();
#pragma unroll
  for (int i = 0; i < 4; ++i) {
    int tt = r + 16 * i;
    alignas(8) u16t hh[4], ll[4];
#pragma unroll
    for (int e = 0; e < 4; ++e) {
      float v = tile[cc + e][tt];
      u16t h = bf16_rtn(v);
      hh[e] = h;
      ll[e] = bf16_rtn(v - bf16f(h));
    }
    size_t o = ((size_t)b * NSEQ + t0 + tt) * DMOD + c0 + cc;
    *reinterpret_cast<ushort4*>(yh + o) = *reinterpret_cast<const ushort4*>(hh);
    *reinterpret_cast<ushort4*>(yl + o) = *reinterpret_cast<const ushort4*>(ll);
  }
}

// ---------------- scores s = h1 @ Wp2 + bp2 (K=256) ----------------
__global__ __launch_bounds__(256) void score_kernel(
    const float* __restrict__ h1, const float* __restrict__ Wp2,
    const float* __restrict__ bp2, float* __restrict__ s) {
  int tid = threadIdx.x;
  int lane = tid & 63, w = tid >> 6;
  int row = blockIdx.x * 4 + w;
  float acc = 0.f;
#pragma unroll
  for (int q = 0; q < 4; ++q) {
    int k = lane + 64 * q;
    acc = fmaf(h1[(size_t)row * 256 + k], Wp2[k], acc);
  }
#pragma unroll
  for (int off = 32; off; off >>= 1) acc += __shfl_down(acc, off);
  if (lane == 0) s[row] = acc + bp2[0];
}

// ---------------- per-batch softmax stats ----------------
__global__ __launch_bounds__(256) void softmax_stats_kernel(
    const float* __restrict__ s, float* __restrict__ bstats) {
  int b = blockIdx.x, tid = threadIdx.x;
  __shared__ float red[256];
  float m = -1e30f;
  for (int n = tid; n < NSEQ; n += 256) m = fmaxf(m, s[b * NSEQ + n]);
  red[tid] = m; __syncthreads();
  for (int o = 128; o; o >>= 1) { if (tid < o) red[tid] = fmaxf(red[tid], red[tid + o]); __syncthreads(); }
  float bm = red[0]; __syncthreads();
  float sum = 0.f;
  for (int n = tid; n < NSEQ; n += 256) sum += expf(s[b * NSEQ + n] - bm);
  red[tid] = sum; __syncthreads();
  for (int o = 128; o; o >>= 1) { if (tid < o) red[tid] += red[tid + o]; __syncthreads(); }
  if (tid == 0) { bstats[b * 2] = bm; bstats[b * 2 + 1] = red[0]; }
}

// ---------------- pooled g ----------------
__global__ __launch_bounds__(256) void pool_partial_kernel(
    const float* __restrict__ x, const float* __restrict__ s,
    const float* __restrict__ bstats, float* __restrict__ gpart) {
  int chunk = blockIdx.x, b = blockIdx.y;
  int tid = threadIdx.x;
  __shared__ float wsh[128];
  float bm = bstats[b * 2], inv = 1.0f / bstats[b * 2 + 1];
  int n0 = chunk * 128;
  if (tid < 128) wsh[tid] = expf(s[b * NSEQ + n0 + tid] - bm) * inv;
  __syncthreads();
  float acc[4] = {};
  for (int n = 0; n < 128; ++n) {
    float wn = wsh[n];
    const float* xr = &x[((size_t)b * NSEQ + n0 + n) * DMOD];
#pragma unroll
    for (int q = 0; q < 4; ++q) acc[q] = fmaf(wn, xr[tid + 256 * q], acc[q]);
  }
  float* gp = &gpart[((size_t)b * 16 + chunk) * DMOD];
#pragma unroll
  for (int q = 0; q < 4; ++q) gp[tid + 256 * q] = acc[q];
}

__global__ __launch_bounds__(256) void pool_reduce_kernel(
    const float* __restrict__ gpart, float* __restrict__ g) {
  int b = blockIdx.x, tid = threadIdx.x;
  for (int d = tid; d < DMOD; d += 256) {
    float acc = 0.f;
    for (int c = 0; c < 16; ++c) acc += gpart[((size_t)b * 16 + c) * DMOD + d];
    g[b * DMOD + d] = acc;
  }
}

// ---------------- gate MLP -> anchors ----------------
__global__ __launch_bounds__(256) void gate_mlp_kernel(
    const float* __restrict__ g, const float* __restrict__ Wg1,
    const float* __restrict__ bg1, const float* __restrict__ Wg2,
    const float* __restrict__ bg2, float* __restrict__ anchors) {
  int b = blockIdx.x, tid = threadIdx.x;
  __shared__ float gs[1024];
  __shared__ float hs[256];
  for (int d = tid; d < 1024; d += 256) gs[d] = g[b * 1024 + d];
  __syncthreads();
  float acc = bg1[tid];
  for (int i = 0; i < 1024; ++i) acc = fmaf(gs[i], Wg1[i * 256 + tid], acc);
  hs[tid] = gelu_exact(acc);
  __syncthreads();
#pragma unroll
  for (int q = 0; q < 4; ++q) {
    int c = tid + 256 * q;
    float a2 = bg2[c];
    for (int i = 0; i < 256; ++i) a2 = fmaf(hs[i], Wg2[i * 1024 + c], a2);
    anchors[b * 1024 + c] = a2;
  }
}

// ---------------- cubic resize + modReLU + complex conv ----------------
__device__ __forceinline__ float keys_cubic(float x) {
  if (x >= 2.0f) return 0.0f;
  if (x >= 1.0f) return ((-0.5f * x + 2.5f) * x - 4.0f) * x + 2.0f;
  return ((1.5f * x - 2.5f) * x) * x + 1.0f;
}

__global__ __launch_bounds__(256) void gate_kernel(
    const float* __restrict__ anchors, const float* __restrict__ mod_bias,
    const float* __restrict__ kr5, const float* __restrict__ ki5,
    float* __restrict__ gate_out) {
  int bh = blockIdx.x;
  int tid = threadIdx.x;
  __shared__ float ar_[32], ai_[32];
  __shared__ float gr[NFREQ], gi[NFREQ];
  if (tid < 32) {
    ar_[tid] = anchors[bh * 64 + tid * 2 + 0];
    ai_[tid] = anchors[bh * 64 + tid * 2 + 1];
  }
  __syncthreads();
  const float inv_scale = 32.0f / 1025.0f;
  for (int f = tid; f < NFREQ; f += 256) {
    float c = (f + 0.5f) * inv_scale - 0.5f;
    int j0 = (int)floorf(c) - 1;
    float wr = 0.f, wi = 0.f, wsum = 0.f;
#pragma unroll
    for (int u = 0; u < 4; ++u) {
      int j = j0 + u;
      if (j < 0 || j > 31) continue;
      float w = keys_cubic(fabsf(c - (float)j));
      wsum += w;
      wr = fmaf(w, ar_[j], wr);
      wi = fmaf(w, ai_[j], wi);
    }
    float invw = 1.0f / wsum;
    wr *= invw; wi *= invw;
    float mag = sqrtf(wr * wr + wi * wi);
    float scale = fmaxf(mag + mod_bias[f], 0.0f) / (mag + 1e-8f);
    gr[f] = wr * scale;
    gi[f] = wi * scale;
  }
  __syncthreads();
  float k_r[5], k_i[5];
#pragma unroll
  for (int j = 0; j < 5; ++j) { k_r[j] = kr5[j]; k_i[j] = ki5[j]; }
  for (int f = tid; f < NFREQ; f += 256) {
    float cr = 0.f, ci = 0.f;
#pragma unroll
    for (int j = 0; j < 5; ++j) {
      int idx = f + j - 2;
      if (idx < 0) idx += NFREQ;
      else if (idx >= NFREQ) idx -= NFREQ;
      float a = gr[idx], bb = gi[idx];
      cr = fmaf(k_r[j], a, cr); cr = fmaf(-k_i[j], bb, cr);
      ci = fmaf(k_r[j], bb, ci); ci = fmaf(k_i[j], a, ci);
    }
    gate_out[((size_t)bh * NFREQ + f) * 2 + 0] = cr;
    gate_out[((size_t)bh * NFREQ + f) * 2 + 1] = ci;
  }
}

extern "C" void kernel_launch(void* const* d_in, const int* in_sizes, int n_in,
                              void* d_out, int out_size, void* d_ws, size_t ws_size,
                              hipStream_t stream) {
  const float* x        = (const float*)d_in[0];
  const float* Wv       = (const float*)d_in[1];
  const float* bv       = (const float*)d_in[2];
  const float* Wp1      = (const float*)d_in[3];
  const float* bp1      = (const float*)d_in[4];
  const float* Wp2      = (const float*)d_in[5];
  const float* bp2      = (const float*)d_in[6];
  const float* Wg1      = (const float*)d_in[7];
  const float* bg1      = (const float*)d_in[8];
  const float* Wg2      = (const float*)d_in[9];
  const float* bg2      = (const float*)d_in[10];
  const float* mod_bias = (const float*)d_in[11];
  const float* ckr      = (const float*)d_in[12];
  const float* cki      = (const float*)d_in[13];
  const float* Wo       = (const float*)d_in[14];
  const float* bo       = (const float*)d_in[15];

  const int M = NBATCH * NSEQ;          // 8192
  const size_t MD = (size_t)M * DMOD;   // 8M elems

  // ws layout (~36.9 MB):
  u16t* x_hi = (u16t*)d_ws;             // 16 MB ; later reused as y split hi
  u16t* x_lo = x_hi + MD;               // 16 MB ; later reused as y split lo
  u16t* y_hi = x_hi;
  u16t* y_lo = x_lo;
  u16t* WT_h = (u16t*)((char*)d_ws + (size_t)32 * 1024 * 1024);  // 2 MB
  u16t* WT_l = WT_h + (size_t)1024 * 1024;                        // 2 MB
  float* smallf = (float*)((char*)d_ws + (size_t)36 * 1024 * 1024);
  float* s       = smallf;              // 8192
  float* bstats  = s + 8192;            // 8
  float* gpart   = bstats + 8;          // 65536
  float* g       = gpart + 65536;       // 4096
  float* anchors = g + 4096;            // 4096
  float* gateb   = anchors + 4096;      // 131200

  // d_out staging: h1 (8 MB fp32) -> vT fp32 (32 MB, in-place FFT -> yT) -> out fp32
  float* h1  = (float*)d_out;
  float* vT  = (float*)d_out;
  float* out = (float*)d_out;

  dim3 blk(256);

  // 0. split x -> bf16 hi/lo
  split_kernel<<<dim3(2048), blk, 0, stream>>>(x, x_hi, x_lo, (int)(MD / 8));
  // 1. Wp1^T split; GEMM2: h1 = gelu(x @ Wp1 + bp1)
  tsplit_kernel<<<dim3(256 / 32, 1024 / 32), blk, 0, stream>>>(Wp1, WT_h, WT_l, 1024, 256);
  mfma_gemm<true, 0><<<dim3(256 / 128, M / 128), blk, 0, stream>>>(
      x_hi, x_lo, WT_h, WT_l, bp1, h1, 256, 1024);
  // 2. scores + softmax + pooled g
  score_kernel<<<dim3(M / 4), blk, 0, stream>>>(h1, Wp2, bp2, s);
  softmax_stats_kernel<<<dim3(NBATCH), blk, 0, stream>>>(s, bstats);
  pool_partial_kernel<<<dim3(16, NBATCH), blk, 0, stream>>>(x, s, bstats, gpart);
  pool_reduce_kernel<<<dim3(NBATCH), blk, 0, stream>>>(gpart, g);
  // 3. gate path
  gate_mlp_kernel<<<dim3(NBATCH), blk, 0, stream>>>(g, Wg1, bg1, Wg2, bg2, anchors);
  gate_kernel<<<dim3(NBATCH * NHEAD), blk, 0, stream>>>(anchors, mod_bias, ckr, cki, gateb);
  // 4. Wv^T split; GEMM1: vT = (x @ Wv + bv)^T fp32 into d_out (h1 dead)
  tsplit_kernel<<<dim3(1024 / 32, 1024 / 32), blk, 0, stream>>>(Wv, WT_h, WT_l, 1024, 1024);
  mfma_gemm<false, 2><<<dim3(DMOD / 128, M / 128), blk, 0, stream>>>(
      x_hi, x_lo, WT_h, WT_l, bv, vT, DMOD, 1024);
  // 5. fused rFFT*gate*irFFT in place on vT -> yT
  conv_fft_kernel<<<dim3(DMOD / 4, NBATCH), blk, 0, stream>>>(vT, gateb);
  // 6. transpose+split: yT -> y split bf16 (overwrites x split; x dead)
  tysplit_kernel<<<dim3(NSEQ / 64, DMOD / 64, NBATCH), blk, 0, stream>>>(vT, y_hi, y_lo);
  // 7. Wo^T split; GEMM3: out = y @ Wo + bo (overwrites yT; dead)
  tsplit_kernel<<<dim3(1024 / 32, 1024 / 32), blk, 0, stream>>>(Wo, WT_h, WT_l, 1024, 1024);
  mfma_gemm<false, 0><<<dim3(DMOD / 128, M / 128), blk, 0, stream>>>(
      y_hi, y_lo, WT_h, WT_l, bo, out, DMOD, 1024);
}

// Round 5
// 273.733 us; speedup vs baseline: 3.9476x; 1.1906x over previous
//
#include <hip/hip_runtime.h>
#include <math.h>

#define NSEQ 2048
#define DMOD 1024
#define NBATCH 4
#define NHEAD 16
#define NFREQ 1025

typedef unsigned short u16t;
typedef __attribute__((ext_vector_type(8))) short short8;
typedef __attribute__((ext_vector_type(4))) float f32x4;

__device__ __forceinline__ float gelu_exact(float x) {
  return 0.5f * x * (1.0f + erff(x * 0.70710678118654752440f));
}
__device__ __forceinline__ u16t bf16_rtn(float x) {
  unsigned u = __float_as_uint(x);
  return (u16t)((u + 0x7FFFu + ((u >> 16) & 1u)) >> 16);
}
__device__ __forceinline__ float bf16f(u16t h) {
  return __uint_as_float(((unsigned)h) << 16);
}
__device__ __forceinline__ void gload_lds16(const u16t* g, u16t* l) {
  __builtin_amdgcn_global_load_lds(
      (const __attribute__((address_space(1))) void*)g,
      (__attribute__((address_space(3))) void*)l, 16, 0, 0);
}

// ---------------- elementwise split fp32 -> bf16 hi/lo ----------------
__global__ __launch_bounds__(256) void split_kernel(const float* __restrict__ in,
    u16t* __restrict__ hi, u16t* __restrict__ lo, int n8) {
  for (int i = blockIdx.x * blockDim.x + threadIdx.x; i < n8; i += gridDim.x * blockDim.x) {
    const float4* p = reinterpret_cast<const float4*>(in + (size_t)i * 8);
    float4 a = p[0], b = p[1];
    float vv[8] = {a.x, a.y, a.z, a.w, b.x, b.y, b.z, b.w};
    alignas(16) u16t th[8];
    alignas(16) u16t tl[8];
#pragma unroll
    for (int e = 0; e < 8; ++e) {
      u16t h = bf16_rtn(vv[e]);
      th[e] = h;
      tl[e] = bf16_rtn(vv[e] - bf16f(h));
    }
    *reinterpret_cast<uint4*>(hi + (size_t)i * 8) = *reinterpret_cast<const uint4*>(th);
    *reinterpret_cast<uint4*>(lo + (size_t)i * 8) = *reinterpret_cast<const uint4*>(tl);
  }
}

// ---------------- transpose + split weights: W[K][N] -> T{h,l}[N][K] ----------------
__global__ __launch_bounds__(256) void tsplit_kernel(const float* __restrict__ W,
    u16t* __restrict__ Th, u16t* __restrict__ Tl, int K, int N) {
  __shared__ float tile[32][33];
  int k0 = blockIdx.y * 32, n0 = blockIdx.x * 32;
  int r = threadIdx.x >> 5, c = threadIdx.x & 31;
#pragma unroll
  for (int i = 0; i < 4; ++i)
    tile[r + 8 * i][c] = W[(size_t)(k0 + r + 8 * i) * N + n0 + c];
  __syncthreads();
#pragma unroll
  for (int i = 0; i < 4; ++i) {
    int rr = r + 8 * i;
    float v = tile[c][rr];
    u16t h = bf16_rtn(v);
    Th[(size_t)(n0 + rr) * K + k0 + c] = h;
    Tl[(size_t)(n0 + rr) * K + k0 + c] = bf16_rtn(v - bf16f(h));
  }
}

// ---------------- split-bf16 MFMA GEMM ----------------
template<bool GELU, int OUTMODE>
__global__ __launch_bounds__(256) void mfma_gemm(
    const u16t* __restrict__ Ah_g, const u16t* __restrict__ Al_g,
    const u16t* __restrict__ Bh_g, const u16t* __restrict__ Bl_g,
    const float* __restrict__ bias,
    float* __restrict__ Cf,
    int N, int K) {
  __shared__ u16t Ahs[128 * 64], Als[128 * 64], Bhs[128 * 64], Bls[128 * 64]; // 64 KB
  const int tid = threadIdx.x;
  const int lane = tid & 63, wave = tid >> 6;
  const int lr = lane & 15, lg = lane >> 4;
  const int wm0 = (wave >> 1) * 64, wn0 = (wave & 1) * 64;
  const int m0 = blockIdx.y * 128, n0 = blockIdx.x * 128;

  f32x4 acc[4][4];
#pragma unroll
  for (int i = 0; i < 4; ++i)
#pragma unroll
    for (int j = 0; j < 4; ++j) acc[i][j] = 0.0f;

  for (int k0 = 0; k0 < K; k0 += 64) {
#pragma unroll
    for (int q = 0; q < 4; ++q) {
      int cid = q * 256 + tid;
      int row = cid >> 3, grp = cid & 7;
      int koff = k0 + ((grp ^ (row & 7)) << 3);
      size_t ea = (size_t)(m0 + row) * K + koff;
      size_t eb = (size_t)(n0 + row) * K + koff;
      int lbase = q * 2048 + wave * 512;
      gload_lds16(Ah_g + ea, Ahs + lbase);
      gload_lds16(Al_g + ea, Als + lbase);
      gload_lds16(Bh_g + eb, Bhs + lbase);
      gload_lds16(Bl_g + eb, Bls + lbase);
    }
    __syncthreads();
#pragma unroll
    for (int kf = 0; kf < 2; ++kf) {
      short8 ah[4], al[4];
#pragma unroll
      for (int mi = 0; mi < 4; ++mi) {
        int r_ = wm0 + mi * 16 + lr;
        int g = (kf * 4 + lg) ^ (r_ & 7);
        ah[mi] = *reinterpret_cast<const short8*>(&Ahs[r_ * 64 + g * 8]);
        al[mi] = *reinterpret_cast<const short8*>(&Als[r_ * 64 + g * 8]);
      }
#pragma unroll
      for (int ni = 0; ni < 4; ++ni) {
        int r_ = wn0 + ni * 16 + lr;
        int g = (kf * 4 + lg) ^ (r_ & 7);
        short8 bh8 = *reinterpret_cast<const short8*>(&Bhs[r_ * 64 + g * 8]);
        short8 bl8 = *reinterpret_cast<const short8*>(&Bls[r_ * 64 + g * 8]);
#pragma unroll
        for (int mi = 0; mi < 4; ++mi) {
          acc[mi][ni] = __builtin_amdgcn_mfma_f32_16x16x32_bf16(ah[mi], bh8, acc[mi][ni], 0, 0, 0);
          acc[mi][ni] = __builtin_amdgcn_mfma_f32_16x16x32_bf16(ah[mi], bl8, acc[mi][ni], 0, 0, 0);
          acc[mi][ni] = __builtin_amdgcn_mfma_f32_16x16x32_bf16(al[mi], bh8, acc[mi][ni], 0, 0, 0);
        }
      }
    }
    __syncthreads();
  }
#pragma unroll
  for (int mi = 0; mi < 4; ++mi)
#pragma unroll
    for (int ni = 0; ni < 4; ++ni) {
      int col = n0 + wn0 + ni * 16 + lr;
      float bv = bias[col];
      f32x4 a = acc[mi][ni];
      if (OUTMODE == 2) {
        int mbase = m0 + wm0 + mi * 16 + lg * 4;
        int b = mbase >> 11, ss = mbase & 2047;
        float4 o4;
        o4.x = a[0] + bv; o4.y = a[1] + bv; o4.z = a[2] + bv; o4.w = a[3] + bv;
        *reinterpret_cast<float4*>(Cf + (size_t)b * (DMOD * NSEQ) + (size_t)col * NSEQ + ss) = o4;
      } else {
#pragma unroll
        for (int r = 0; r < 4; ++r) {
          int row = m0 + wm0 + mi * 16 + lg * 4 + r;
          float val = a[r] + bv;
          if (GELU) val = gelu_exact(val);
          Cf[(size_t)row * N + col] = val;
        }
      }
    }
}

// ---------------- fused rFFT * gate * irFFT, in place on vT[b][c][s] ----------------
__global__ __launch_bounds__(256) void conv_fft_kernel(
    float* __restrict__ vio, const float* __restrict__ gateb) {
  __shared__ float2 Z[4][1024];    // 32 KB
  __shared__ float2 TW[512];
  __shared__ float2 TWH[512];
  const int tid = threadIdx.x;
  const int lane = tid & 63, wave = tid >> 6;
  const int c0 = blockIdx.x * 4;
  const int b = blockIdx.y;
  const int bh = b * NHEAD + (c0 >> 6);
  const float* gate_bh = gateb + (size_t)bh * NFREQ * 2;

#pragma unroll
  for (int q = 0; q < 2; ++q) {
    int m = q * 256 + tid;
    float si, co;
    sincosf(-3.14159265358979323846f * (float)m * (1.0f / 512.0f), &si, &co);
    TW[m] = make_float2(co, si);
    float si2, co2;
    sincosf(-3.14159265358979323846f * (float)m * (1.0f / 1024.0f), &si2, &co2);
    TWH[m] = make_float2(co2, si2);
  }
  __syncthreads();

  float2* Zc = Z[wave];
  float* col = vio + ((size_t)b * DMOD + (c0 + wave)) * NSEQ;

#pragma unroll
  for (int q = 0; q < 8; ++q) {
    int i4 = q * 64 + lane;
    float4 w4 = *reinterpret_cast<const float4*>(col + i4 * 4);
    *reinterpret_cast<float4*>(&Zc[2 * i4]) = w4;
  }
  asm volatile("s_waitcnt lgkmcnt(0)" ::: "memory");

  for (int lh = 9; lh >= 0; --lh) {
    int h = 1 << lh;
#pragma unroll
    for (int q = 0; q < 8; ++q) {
      int m = q * 64 + lane;
      int j = m & (h - 1);
      int base = ((m >> lh) << (lh + 1)) | j;
      float2 u = Zc[base], v = Zc[base + h];
      float2 tw = TW[j << (9 - lh)];
      float dx = u.x - v.x, dy = u.y - v.y;
      Zc[base] = make_float2(u.x + v.x, u.y + v.y);
      Zc[base + h] = make_float2(dx * tw.x - dy * tw.y, dx * tw.y + dy * tw.x);
    }
    asm volatile("s_waitcnt lgkmcnt(0)" ::: "memory");
  }

  const float s1 = 1.0f / 1024.0f;
#pragma unroll
  for (int q = 0; q < 8; ++q) {
    int k = q * 64 + lane;
    if (k == 0) {
      float2 Z0 = Zc[0];
      float X0 = Z0.x + Z0.y;
      float XN = Z0.x - Z0.y;
      float2 G0 = *reinterpret_cast<const float2*>(gate_bh + 0);
      float2 GN = *reinterpret_cast<const float2*>(gate_bh + 1024 * 2);
      float y0 = X0 * G0.x * s1;
      float yN = XN * GN.x * s1;
      Zc[0] = make_float2(0.5f * (y0 + yN), 0.5f * (y0 - yN));
      float2 Zm = Zc[1];
      float2 X5 = make_float2(Zm.x, -Zm.y);
      float2 G5 = *reinterpret_cast<const float2*>(gate_bh + 512 * 2);
      float2 Y5 = make_float2((X5.x * G5.x - X5.y * G5.y) * s1,
                              (X5.x * G5.y + X5.y * G5.x) * s1);
      Zc[1] = make_float2(Y5.x, -Y5.y);
    } else {
      int kq = 1024 - k;
      int rp = __brev((unsigned)k) >> 22;
      int rq = __brev((unsigned)kq) >> 22;
      float2 Zk = Zc[rp], Zq = Zc[rq];
      float Er = 0.5f * (Zk.x + Zq.x), Ei = 0.5f * (Zk.y - Zq.y);
      float Odr = 0.5f * (Zk.y + Zq.y), Odi = -0.5f * (Zk.x - Zq.x);
      float2 t = TWH[k];
      float Pr = Odr * t.x - Odi * t.y, Pi = Odr * t.y + Odi * t.x;
      float2 Xk = make_float2(Er + Pr, Ei + Pi);
      float2 Xq = make_float2(Er - Pr, -(Ei - Pi));
      float2 Gk = *reinterpret_cast<const float2*>(gate_bh + k * 2);
      float2 Gq = *reinterpret_cast<const float2*>(gate_bh + kq * 2);
      float2 Yk = make_float2((Xk.x * Gk.x - Xk.y * Gk.y) * s1,
                              (Xk.x * Gk.y + Xk.y * Gk.x) * s1);
      float2 Yq = make_float2((Xq.x * Gq.x - Xq.y * Gq.y) * s1,
                              (Xq.x * Gq.y + Xq.y * Gq.x) * s1);
      float E2r = 0.5f * (Yk.x + Yq.x), E2i = 0.5f * (Yk.y - Yq.y);
      float D2r = 0.5f * (Yk.x - Yq.x), D2i = 0.5f * (Yk.y + Yq.y);
      float O2r = D2r * t.x + D2i * t.y, O2i = D2i * t.x - D2r * t.y;
      Zc[rp] = make_float2(E2r - O2i, E2i + O2r);
      Zc[rq] = make_float2(E2r + O2i, O2r - E2i);
    }
  }
  asm volatile("s_waitcnt lgkmcnt(0)" ::: "memory");

  for (int lh = 0; lh <= 9; ++lh) {
    int h = 1 << lh;
#pragma unroll
    for (int q = 0; q < 8; ++q) {
      int m = q * 64 + lane;
      int j = m & (h - 1);
      int base = ((m >> lh) << (lh + 1)) | j;
      float2 u = Zc[base], v = Zc[base + h];
      float2 tw = TW[j << (9 - lh)];
      float tx = v.x * tw.x + v.y * tw.y, ty = v.y * tw.x - v.x * tw.y;
      Zc[base] = make_float2(u.x + tx, u.y + ty);
      Zc[base + h] = make_float2(u.x - tx, u.y - ty);
    }
    asm volatile("s_waitcnt lgkmcnt(0)" ::: "memory");
  }

#pragma unroll
  for (int q = 0; q < 8; ++q) {
    int i4 = q * 64 + lane;
    float4 w4 = *reinterpret_cast<const float4*>(&Zc[2 * i4]);
    *reinterpret_cast<float4*>(col + i4 * 4) = w4;
  }
}

// ---------------- transpose + split: yT[b][c][t] fp32 -> y{h,l}[b][t][c] bf16 ----------------
__global__ __launch_bounds__(256) void tysplit_kernel(
    const float* __restrict__ yT, u16t* __restrict__ yh, u16t* __restrict__ yl) {
  __shared__ float tile[64][65];
  int t0 = blockIdx.x * 64, c0 = blockIdx.y * 64, b = blockIdx.z;
  int r = threadIdx.x >> 4;
  int cc = (threadIdx.x & 15) * 4;
#pragma unroll
  for (int i = 0; i < 4; ++i) {
    int row = r + 16 * i;
    float4 w = *reinterpret_cast<const float4*>(
        yT + ((size_t)b * DMOD + c0 + row) * NSEQ + t0 + cc);
    tile[row][cc] = w.x; tile[row][cc + 1] = w.y;
    tile[row][cc + 2] = w.z; tile[row][cc + 3] = w.w;
  }
  __syncthreads();
#pragma unroll
  for (int i = 0; i < 4; ++i) {
    int tt = r + 16 * i;
    alignas(8) u16t hh[4], ll[4];
#pragma unroll
    for (int e = 0; e < 4; ++e) {
      float v = tile[cc + e][tt];
      u16t h = bf16_rtn(v);
      hh[e] = h;
      ll[e] = bf16_rtn(v - bf16f(h));
    }
    size_t o = ((size_t)b * NSEQ + t0 + tt) * DMOD + c0 + cc;
    *reinterpret_cast<ushort4*>(yh + o) = *reinterpret_cast<const ushort4*>(hh);
    *reinterpret_cast<ushort4*>(yl + o) = *reinterpret_cast<const ushort4*>(ll);
  }
}

// ---------------- scores s = h1 @ Wp2 + bp2 (K=256) ----------------
__global__ __launch_bounds__(256) void score_kernel(
    const float* __restrict__ h1, const float* __restrict__ Wp2,
    const float* __restrict__ bp2, float* __restrict__ s) {
  int tid = threadIdx.x;
  int lane = tid & 63, w = tid >> 6;
  int row = blockIdx.x * 4 + w;
  float acc = 0.f;
#pragma unroll
  for (int q = 0; q < 4; ++q) {
    int k = lane + 64 * q;
    acc = fmaf(h1[(size_t)row * 256 + k], Wp2[k], acc);
  }
#pragma unroll
  for (int off = 32; off; off >>= 1) acc += __shfl_down(acc, off);
  if (lane == 0) s[row] = acc + bp2[0];
}

// ---------------- per-batch softmax stats ----------------
__global__ __launch_bounds__(256) void softmax_stats_kernel(
    const float* __restrict__ s, float* __restrict__ bstats) {
  int b = blockIdx.x, tid = threadIdx.x;
  __shared__ float red[256];
  float m = -1e30f;
  for (int n = tid; n < NSEQ; n += 256) m = fmaxf(m, s[b * NSEQ + n]);
  red[tid] = m; __syncthreads();
  for (int o = 128; o; o >>= 1) { if (tid < o) red[tid] = fmaxf(red[tid], red[tid + o]); __syncthreads(); }
  float bm = red[0]; __syncthreads();
  float sum = 0.f;
  for (int n = tid; n < NSEQ; n += 256) sum += expf(s[b * NSEQ + n] - bm);
  red[tid] = sum; __syncthreads();
  for (int o = 128; o; o >>= 1) { if (tid < o) red[tid] += red[tid + o]; __syncthreads(); }
  if (tid == 0) { bstats[b * 2] = bm; bstats[b * 2 + 1] = red[0]; }
}

// ---------------- pooled g partials ----------------
__global__ __launch_bounds__(256) void pool_partial_kernel(
    const float* __restrict__ x, const float* __restrict__ s,
    const float* __restrict__ bstats, float* __restrict__ gpart) {
  int chunk = blockIdx.x, b = blockIdx.y;
  int tid = threadIdx.x;
  __shared__ float wsh[128];
  float bm = bstats[b * 2], inv = 1.0f / bstats[b * 2 + 1];
  int n0 = chunk * 128;
  if (tid < 128) wsh[tid] = expf(s[b * NSEQ + n0 + tid] - bm) * inv;
  __syncthreads();
  float acc[4] = {};
  for (int n = 0; n < 128; ++n) {
    float wn = wsh[n];
    const float* xr = &x[((size_t)b * NSEQ + n0 + n) * DMOD];
#pragma unroll
    for (int q = 0; q < 4; ++q) acc[q] = fmaf(wn, xr[tid + 256 * q], acc[q]);
  }
  float* gp = &gpart[((size_t)b * 16 + chunk) * DMOD];
#pragma unroll
  for (int q = 0; q < 4; ++q) gp[tid + 256 * q] = acc[q];
}

// ---------------- fused pool-reduce + MLP1 partial ----------------
// grid (16 kb, 4 b): g-slice (64 wide) from gpart, then partial g@Wg1 for all 256 units.
__global__ __launch_bounds__(256) void pool_reduce_mlp1_kernel(
    const float* __restrict__ gpart, const float* __restrict__ Wg1,
    float* __restrict__ part1) {
  int kb = blockIdx.x, b = blockIdx.y;
  int tid = threadIdx.x;
  int k0 = kb * 64;
  __shared__ float g_s[64];
  if (tid < 64) {
    float acc = 0.f;
#pragma unroll
    for (int j = 0; j < 16; ++j)
      acc += gpart[((size_t)b * 16 + j) * DMOD + k0 + tid];
    g_s[tid] = acc;
  }
  __syncthreads();
  float acc = 0.f;
#pragma unroll 8
  for (int i = 0; i < 64; ++i)
    acc = fmaf(g_s[i], Wg1[(size_t)(k0 + i) * 256 + tid], acc);
  part1[((size_t)b * 16 + kb) * 256 + tid] = acc;
}

// ---------------- fused MLP1-reduce+gelu + MLP2 partial ----------------
// grid (4 kb2, 2 nh, 4 b): hs-slice (64) then partial hs@Wg2 for 512 outputs.
__global__ __launch_bounds__(256) void mlp1red_mlp2_kernel(
    const float* __restrict__ part1, const float* __restrict__ bg1,
    const float* __restrict__ Wg2, float* __restrict__ part2) {
  int kb2 = blockIdx.x, nh = blockIdx.y, b = blockIdx.z;
  int tid = threadIdx.x;
  int k0 = kb2 * 64;
  __shared__ float hs_s[64];
  if (tid < 64) {
    float acc = bg1[k0 + tid];
#pragma unroll
    for (int j = 0; j < 16; ++j)
      acc += part1[((size_t)b * 16 + j) * 256 + k0 + tid];
    hs_s[tid] = gelu_exact(acc);
  }
  __syncthreads();
  float acc[2] = {};
#pragma unroll 8
  for (int i = 0; i < 64; ++i) {
    float hv = hs_s[i];
    const float* wr = &Wg2[(size_t)(k0 + i) * 1024 + nh * 512];
    acc[0] = fmaf(hv, wr[tid], acc[0]);
    acc[1] = fmaf(hv, wr[tid + 256], acc[1]);
  }
  float* pp = &part2[((size_t)b * 4 + kb2) * 1024 + nh * 512];
  pp[tid] = acc[0];
  pp[tid + 256] = acc[1];
}

// ---------------- anchors-reduce + cubic resize + modReLU + complex conv ----------------
__device__ __forceinline__ float keys_cubic(float x) {
  if (x >= 2.0f) return 0.0f;
  if (x >= 1.0f) return ((-0.5f * x + 2.5f) * x - 4.0f) * x + 2.0f;
  return ((1.5f * x - 2.5f) * x) * x + 1.0f;
}

__global__ __launch_bounds__(256) void gate_kernel(
    const float* __restrict__ part2, const float* __restrict__ bg2,
    const float* __restrict__ mod_bias,
    const float* __restrict__ kr5, const float* __restrict__ ki5,
    float* __restrict__ gate_out) {
  int bh = blockIdx.x;
  int tid = threadIdx.x;
  __shared__ float anch_s[64];
  __shared__ float ar_[32], ai_[32];
  __shared__ float gr[NFREQ], gi[NFREQ];
  int b = bh >> 4, h = bh & 15;
  if (tid < 64) {
    int cc = h * 64 + tid;
    float acc = bg2[cc];
#pragma unroll
    for (int j = 0; j < 4; ++j)
      acc += part2[((size_t)b * 4 + j) * 1024 + cc];
    anch_s[tid] = acc;
  }
  __syncthreads();
  if (tid < 32) {
    ar_[tid] = anch_s[tid * 2 + 0];
    ai_[tid] = anch_s[tid * 2 + 1];
  }
  __syncthreads();
  const float inv_scale = 32.0f / 1025.0f;
  for (int f = tid; f < NFREQ; f += 256) {
    float c = (f + 0.5f) * inv_scale - 0.5f;
    int j0 = (int)floorf(c) - 1;
    float wr = 0.f, wi = 0.f, wsum = 0.f;
#pragma unroll
    for (int u = 0; u < 4; ++u) {
      int j = j0 + u;
      if (j < 0 || j > 31) continue;
      float w = keys_cubic(fabsf(c - (float)j));
      wsum += w;
      wr = fmaf(w, ar_[j], wr);
      wi = fmaf(w, ai_[j], wi);
    }
    float invw = 1.0f / wsum;
    wr *= invw; wi *= invw;
    float mag = sqrtf(wr * wr + wi * wi);
    float scale = fmaxf(mag + mod_bias[f], 0.0f) / (mag + 1e-8f);
    gr[f] = wr * scale;
    gi[f] = wi * scale;
  }
  __syncthreads();
  float k_r[5], k_i[5];
#pragma unroll
  for (int j = 0; j < 5; ++j) { k_r[j] = kr5[j]; k_i[j] = ki5[j]; }
  for (int f = tid; f < NFREQ; f += 256) {
    float cr = 0.f, ci = 0.f;
#pragma unroll
    for (int j = 0; j < 5; ++j) {
      int idx = f + j - 2;
      if (idx < 0) idx += NFREQ;
      else if (idx >= NFREQ) idx -= NFREQ;
      float a = gr[idx], bb = gi[idx];
      cr = fmaf(k_r[j], a, cr); cr = fmaf(-k_i[j], bb, cr);
      ci = fmaf(k_r[j], bb, ci); ci = fmaf(k_i[j], a, ci);
    }
    gate_out[((size_t)bh * NFREQ + f) * 2 + 0] = cr;
    gate_out[((size_t)bh * NFREQ + f) * 2 + 1] = ci;
  }
}

extern "C" void kernel_launch(void* const* d_in, const int* in_sizes, int n_in,
                              void* d_out, int out_size, void* d_ws, size_t ws_size,
                              hipStream_t stream) {
  const float* x        = (const float*)d_in[0];
  const float* Wv       = (const float*)d_in[1];
  const float* bv       = (const float*)d_in[2];
  const float* Wp1      = (const float*)d_in[3];
  const float* bp1      = (const float*)d_in[4];
  const float* Wp2      = (const float*)d_in[5];
  const float* bp2      = (const float*)d_in[6];
  const float* Wg1      = (const float*)d_in[7];
  const float* bg1      = (const float*)d_in[8];
  const float* Wg2      = (const float*)d_in[9];
  const float* bg2      = (const float*)d_in[10];
  const float* mod_bias = (const float*)d_in[11];
  const float* ckr      = (const float*)d_in[12];
  const float* cki      = (const float*)d_in[13];
  const float* Wo       = (const float*)d_in[14];
  const float* bo       = (const float*)d_in[15];

  const int M = NBATCH * NSEQ;          // 8192
  const size_t MD = (size_t)M * DMOD;   // 8M elems

  // ws layout:
  u16t* x_hi = (u16t*)d_ws;             // 16 MB ; later reused as y split hi
  u16t* x_lo = x_hi + MD;               // 16 MB ; later reused as y split lo
  u16t* y_hi = x_hi;
  u16t* y_lo = x_lo;
  u16t* WT_h = (u16t*)((char*)d_ws + (size_t)32 * 1024 * 1024);  // 2 MB
  u16t* WT_l = WT_h + (size_t)1024 * 1024;                        // 2 MB
  // part1/part2 alias the WT region (WT(Wp1) is dead when these run):
  float* part1 = (float*)WT_h;                  // 16 KB
  float* part2 = part1 + 4 * 16 * 256;          // 16 KB
  float* smallf = (float*)((char*)d_ws + (size_t)36 * 1024 * 1024);
  float* s       = smallf;              // 8192
  float* bstats  = s + 8192;            // 8
  float* gpart   = bstats + 8;          // 65536
  float* gateb   = gpart + 65536;       // 131200

  // d_out staging: h1 (8 MB fp32) -> vT fp32 (32 MB, in-place FFT -> yT) -> out fp32
  float* h1  = (float*)d_out;
  float* vT  = (float*)d_out;
  float* out = (float*)d_out;

  dim3 blk(256);

  // 0. split x -> bf16 hi/lo
  split_kernel<<<dim3(2048), blk, 0, stream>>>(x, x_hi, x_lo, (int)(MD / 8));
  // 1. Wp1^T split; GEMM2: h1 = gelu(x @ Wp1 + bp1)
  tsplit_kernel<<<dim3(256 / 32, 1024 / 32), blk, 0, stream>>>(Wp1, WT_h, WT_l, 1024, 256);
  mfma_gemm<true, 0><<<dim3(256 / 128, M / 128), blk, 0, stream>>>(
      x_hi, x_lo, WT_h, WT_l, bp1, h1, 256, 1024);
  // 2. scores + softmax + pooled g partials
  score_kernel<<<dim3(M / 4), blk, 0, stream>>>(h1, Wp2, bp2, s);
  softmax_stats_kernel<<<dim3(NBATCH), blk, 0, stream>>>(s, bstats);
  pool_partial_kernel<<<dim3(16, NBATCH), blk, 0, stream>>>(x, s, bstats, gpart);
  // 3. gate MLP (parallel K-split; WT(Wp1) dead -> part1/part2 alias it)
  pool_reduce_mlp1_kernel<<<dim3(16, NBATCH), blk, 0, stream>>>(gpart, Wg1, part1);
  mlp1red_mlp2_kernel<<<dim3(4, 2, NBATCH), blk, 0, stream>>>(part1, bg1, Wg2, part2);
  gate_kernel<<<dim3(NBATCH * NHEAD), blk, 0, stream>>>(part2, bg2, mod_bias, ckr, cki, gateb);
  // 4. Wv^T split; GEMM1: vT = (x @ Wv + bv)^T fp32 into d_out (h1 dead)
  tsplit_kernel<<<dim3(1024 / 32, 1024 / 32), blk, 0, stream>>>(Wv, WT_h, WT_l, 1024, 1024);
  mfma_gemm<false, 2><<<dim3(DMOD / 128, M / 128), blk, 0, stream>>>(
      x_hi, x_lo, WT_h, WT_l, bv, vT, DMOD, 1024);
  // 5. fused rFFT*gate*irFFT in place on vT -> yT
  conv_fft_kernel<<<dim3(DMOD / 4, NBATCH), blk, 0, stream>>>(vT, gateb);
  // 6. transpose+split: yT -> y split bf16 (overwrites x split; x dead)
  tysplit_kernel<<<dim3(NSEQ / 64, DMOD / 64, NBATCH), blk, 0, stream>>>(vT, y_hi, y_lo);
  // 7. Wo^T split; GEMM3: out = y @ Wo + bo (overwrites yT; dead)
  tsplit_kernel<<<dim3(1024 / 32, 1024 / 32), blk, 0, stream>>>(Wo, WT_h, WT_l, 1024, 1024);
  mfma_gemm<false, 0><<<dim3(DMOD / 128, M / 128), blk, 0, stream>>>(
      y_hi, y_lo, WT_h, WT_l, bo, out, DMOD, 1024);
}

// Round 6
// 266.789 us; speedup vs baseline: 4.0504x; 1.0260x over previous
//
#include <hip/hip_runtime.h>
#include <math.h>

#define NSEQ 2048
#define DMOD 1024
#define NBATCH 4
#define NHEAD 16
#define NFREQ 1025

typedef unsigned short u16t;
typedef __attribute__((ext_vector_type(8))) short short8;
typedef __attribute__((ext_vector_type(4))) float f32x4;

__device__ __forceinline__ float gelu_exact(float x) {
  return 0.5f * x * (1.0f + erff(x * 0.70710678118654752440f));
}
__device__ __forceinline__ u16t bf16_rtn(float x) {
  unsigned u = __float_as_uint(x);
  return (u16t)((u + 0x7FFFu + ((u >> 16) & 1u)) >> 16);
}
__device__ __forceinline__ float bf16f(u16t h) {
  return __uint_as_float(((unsigned)h) << 16);
}
__device__ __forceinline__ void gload_lds16(const u16t* g, u16t* l) {
  __builtin_amdgcn_global_load_lds(
      (const __attribute__((address_space(1))) void*)g,
      (__attribute__((address_space(3))) void*)l, 16, 0, 0);
}

// ---------------- elementwise split fp32 -> bf16 hi/lo ----------------
__global__ __launch_bounds__(256) void split_kernel(const float* __restrict__ in,
    u16t* __restrict__ hi, u16t* __restrict__ lo, int n8) {
  for (int i = blockIdx.x * blockDim.x + threadIdx.x; i < n8; i += gridDim.x * blockDim.x) {
    const float4* p = reinterpret_cast<const float4*>(in + (size_t)i * 8);
    float4 a = p[0], b = p[1];
    float vv[8] = {a.x, a.y, a.z, a.w, b.x, b.y, b.z, b.w};
    alignas(16) u16t th[8];
    alignas(16) u16t tl[8];
#pragma unroll
    for (int e = 0; e < 8; ++e) {
      u16t h = bf16_rtn(vv[e]);
      th[e] = h;
      tl[e] = bf16_rtn(vv[e] - bf16f(h));
    }
    *reinterpret_cast<uint4*>(hi + (size_t)i * 8) = *reinterpret_cast<const uint4*>(th);
    *reinterpret_cast<uint4*>(lo + (size_t)i * 8) = *reinterpret_cast<const uint4*>(tl);
  }
}

// ---------------- transpose + split weights: W[K][N] -> T{h,l}[N][K] ----------------
__global__ __launch_bounds__(256) void tsplit_kernel(const float* __restrict__ W,
    u16t* __restrict__ Th, u16t* __restrict__ Tl, int K, int N) {
  __shared__ float tile[32][33];
  int k0 = blockIdx.y * 32, n0 = blockIdx.x * 32;
  int r = threadIdx.x >> 5, c = threadIdx.x & 31;
#pragma unroll
  for (int i = 0; i < 4; ++i)
    tile[r + 8 * i][c] = W[(size_t)(k0 + r + 8 * i) * N + n0 + c];
  __syncthreads();
#pragma unroll
  for (int i = 0; i < 4; ++i) {
    int rr = r + 8 * i;
    float v = tile[c][rr];
    u16t h = bf16_rtn(v);
    Th[(size_t)(n0 + rr) * K + k0 + c] = h;
    Tl[(size_t)(n0 + rr) * K + k0 + c] = bf16_rtn(v - bf16f(h));
  }
}

// ---------------- split-bf16 MFMA GEMM ----------------
template<bool GELU, int OUTMODE>
__global__ __launch_bounds__(256) void mfma_gemm(
    const u16t* __restrict__ Ah_g, const u16t* __restrict__ Al_g,
    const u16t* __restrict__ Bh_g, const u16t* __restrict__ Bl_g,
    const float* __restrict__ bias,
    float* __restrict__ Cf,
    int N, int K) {
  __shared__ u16t Ahs[128 * 64], Als[128 * 64], Bhs[128 * 64], Bls[128 * 64]; // 64 KB
  const int tid = threadIdx.x;
  const int lane = tid & 63, wave = tid >> 6;
  const int lr = lane & 15, lg = lane >> 4;
  const int wm0 = (wave >> 1) * 64, wn0 = (wave & 1) * 64;
  const int m0 = blockIdx.y * 128, n0 = blockIdx.x * 128;

  f32x4 acc[4][4];
#pragma unroll
  for (int i = 0; i < 4; ++i)
#pragma unroll
    for (int j = 0; j < 4; ++j) acc[i][j] = 0.0f;

  for (int k0 = 0; k0 < K; k0 += 64) {
#pragma unroll
    for (int q = 0; q < 4; ++q) {
      int cid = q * 256 + tid;
      int row = cid >> 3, grp = cid & 7;
      int koff = k0 + ((grp ^ (row & 7)) << 3);
      size_t ea = (size_t)(m0 + row) * K + koff;
      size_t eb = (size_t)(n0 + row) * K + koff;
      int lbase = q * 2048 + wave * 512;
      gload_lds16(Ah_g + ea, Ahs + lbase);
      gload_lds16(Al_g + ea, Als + lbase);
      gload_lds16(Bh_g + eb, Bhs + lbase);
      gload_lds16(Bl_g + eb, Bls + lbase);
    }
    __syncthreads();
#pragma unroll
    for (int kf = 0; kf < 2; ++kf) {
      short8 ah[4], al[4];
#pragma unroll
      for (int mi = 0; mi < 4; ++mi) {
        int r_ = wm0 + mi * 16 + lr;
        int g = (kf * 4 + lg) ^ (r_ & 7);
        ah[mi] = *reinterpret_cast<const short8*>(&Ahs[r_ * 64 + g * 8]);
        al[mi] = *reinterpret_cast<const short8*>(&Als[r_ * 64 + g * 8]);
      }
#pragma unroll
      for (int ni = 0; ni < 4; ++ni) {
        int r_ = wn0 + ni * 16 + lr;
        int g = (kf * 4 + lg) ^ (r_ & 7);
        short8 bh8 = *reinterpret_cast<const short8*>(&Bhs[r_ * 64 + g * 8]);
        short8 bl8 = *reinterpret_cast<const short8*>(&Bls[r_ * 64 + g * 8]);
#pragma unroll
        for (int mi = 0; mi < 4; ++mi) {
          acc[mi][ni] = __builtin_amdgcn_mfma_f32_16x16x32_bf16(ah[mi], bh8, acc[mi][ni], 0, 0, 0);
          acc[mi][ni] = __builtin_amdgcn_mfma_f32_16x16x32_bf16(ah[mi], bl8, acc[mi][ni], 0, 0, 0);
          acc[mi][ni] = __builtin_amdgcn_mfma_f32_16x16x32_bf16(al[mi], bh8, acc[mi][ni], 0, 0, 0);
        }
      }
    }
    __syncthreads();
  }
#pragma unroll
  for (int mi = 0; mi < 4; ++mi)
#pragma unroll
    for (int ni = 0; ni < 4; ++ni) {
      int col = n0 + wn0 + ni * 16 + lr;
      float bv = bias[col];
      f32x4 a = acc[mi][ni];
      if (OUTMODE == 2) {
        int mbase = m0 + wm0 + mi * 16 + lg * 4;
        int b = mbase >> 11, ss = mbase & 2047;
        float4 o4;
        o4.x = a[0] + bv; o4.y = a[1] + bv; o4.z = a[2] + bv; o4.w = a[3] + bv;
        *reinterpret_cast<float4*>(Cf + (size_t)b * (DMOD * NSEQ) + (size_t)col * NSEQ + ss) = o4;
      } else {
#pragma unroll
        for (int r = 0; r < 4; ++r) {
          int row = m0 + wm0 + mi * 16 + lg * 4 + r;
          float val = a[r] + bv;
          if (GELU) val = gelu_exact(val);
          Cf[(size_t)row * N + col] = val;
        }
      }
    }
}

// ---------------- fused rFFT * gate * irFFT, in place on vT[b][c][s] ----------------
// SoA + pad-per-32 LDS layout: every butterfly/scatter access is <=2-way (free).
#define PADI(i) ((i) + ((i) >> 5))
__global__ __launch_bounds__(256) void conv_fft_kernel(
    float* __restrict__ vio, const float* __restrict__ gateb) {
  __shared__ float Zr[4][1056], Zi[4][1056];   // padded SoA, 33.8 KB
  __shared__ float TWr[528], TWi[528];         // e^{-2pi i m/1024}, padded SoA
  __shared__ float THr[528], THi[528];         // e^{-pi  i k/1024}, padded SoA
  const int tid = threadIdx.x;
  const int lane = tid & 63, wave = tid >> 6;
  const int c0 = blockIdx.x * 4;
  const int b = blockIdx.y;
  const int bh = b * NHEAD + (c0 >> 6);
  const float* gate_bh = gateb + (size_t)bh * NFREQ * 2;

#pragma unroll
  for (int q = 0; q < 2; ++q) {
    int m = q * 256 + tid;
    float si, co;
    sincosf(-3.14159265358979323846f * (float)m * (1.0f / 512.0f), &si, &co);
    TWr[PADI(m)] = co; TWi[PADI(m)] = si;
    float si2, co2;
    sincosf(-3.14159265358979323846f * (float)m * (1.0f / 1024.0f), &si2, &co2);
    THr[PADI(m)] = co2; THi[PADI(m)] = si2;
  }
  __syncthreads();

  float* zr = Zr[wave];
  float* zi = Zi[wave];
  float* col = vio + ((size_t)b * DMOD + (c0 + wave)) * NSEQ;

  // load packed z[n] = v[2n] + i v[2n+1]
#pragma unroll
  for (int q = 0; q < 8; ++q) {
    int i4 = q * 64 + lane;
    float4 w4 = *reinterpret_cast<const float4*>(col + i4 * 4);
    int n0 = 2 * i4;
    int p0 = PADI(n0);                      // n0 even -> n0+1 same pad block
    zr[p0] = w4.x; zi[p0] = w4.y;
    zr[p0 + 1] = w4.z; zi[p0 + 1] = w4.w;
  }
  asm volatile("s_waitcnt lgkmcnt(0)" ::: "memory");

  // forward DIF, 10 stages (bit-reversed output)
  for (int lh = 9; lh >= 0; --lh) {
    int h = 1 << lh;
#pragma unroll
    for (int q = 0; q < 8; ++q) {
      int m = q * 64 + lane;
      int j = m & (h - 1);
      int base = ((m >> lh) << (lh + 1)) | j;
      int ib = PADI(base), ih = PADI(base + h);
      float ur = zr[ib], ui = zi[ib];
      float vr = zr[ih], vi = zi[ih];
      int tj = PADI(j << (9 - lh));
      float twr = TWr[tj], twi = TWi[tj];
      float dr = ur - vr, di = ui - vi;
      zr[ib] = ur + vr; zi[ib] = ui + vi;
      zr[ih] = dr * twr - di * twi;
      zi[ih] = dr * twi + di * twr;
    }
    asm volatile("s_waitcnt lgkmcnt(0)" ::: "memory");
  }

  // untangle -> X[k]; Y = X*G/1024; retangle -> stored bit-reversed (k in [0,512))
  const float s1 = 1.0f / 1024.0f;
#pragma unroll
  for (int q = 0; q < 8; ++q) {
    int k = q * 64 + lane;
    if (k == 0) {
      float z0r = zr[0], z0i = zi[0];
      float X0 = z0r + z0i;
      float XN = z0r - z0i;
      float2 G0 = *reinterpret_cast<const float2*>(gate_bh + 0);
      float2 GN = *reinterpret_cast<const float2*>(gate_bh + 1024 * 2);
      float y0 = X0 * G0.x * s1;    // irfft uses Re only at DC/Nyquist
      float yN = XN * GN.x * s1;
      zr[0] = 0.5f * (y0 + yN); zi[0] = 0.5f * (y0 - yN);
      // k = 512: X = conj(Z[rev(512)=1]); W = conj(Y)
      float zmr = zr[1], zmi = zi[1];
      float X5r = zmr, X5i = -zmi;
      float2 G5 = *reinterpret_cast<const float2*>(gate_bh + 512 * 2);
      float Y5r = (X5r * G5.x - X5i * G5.y) * s1;
      float Y5i = (X5r * G5.y + X5i * G5.x) * s1;
      zr[1] = Y5r; zi[1] = -Y5i;
    } else {
      int kq = 1024 - k;
      int rp = PADI((int)(__brev((unsigned)k) >> 22));
      int rq = PADI((int)(__brev((unsigned)kq) >> 22));
      float Zkr = zr[rp], Zki = zi[rp];
      float Zqr = zr[rq], Zqi = zi[rq];
      float Er = 0.5f * (Zkr + Zqr), Ei = 0.5f * (Zki - Zqi);
      float Odr = 0.5f * (Zki + Zqi), Odi = -0.5f * (Zkr - Zqr);
      int tk = PADI(k);
      float tr = THr[tk], ti = THi[tk];
      float Pr = Odr * tr - Odi * ti, Pi = Odr * ti + Odi * tr;
      float Xkr = Er + Pr, Xki = Ei + Pi;
      float Xqr = Er - Pr, Xqi = -(Ei - Pi);
      float2 Gk = *reinterpret_cast<const float2*>(gate_bh + k * 2);
      float2 Gq = *reinterpret_cast<const float2*>(gate_bh + kq * 2);
      float Ykr = (Xkr * Gk.x - Xki * Gk.y) * s1;
      float Yki = (Xkr * Gk.y + Xki * Gk.x) * s1;
      float Yqr = (Xqr * Gq.x - Xqi * Gq.y) * s1;
      float Yqi = (Xqr * Gq.y + Xqi * Gq.x) * s1;
      float E2r = 0.5f * (Ykr + Yqr), E2i = 0.5f * (Yki - Yqi);
      float D2r = 0.5f * (Ykr - Yqr), D2i = 0.5f * (Yki + Yqi);
      float O2r = D2r * tr + D2i * ti, O2i = D2i * tr - D2r * ti;
      zr[rp] = E2r - O2i; zi[rp] = E2i + O2r;   // W[k]  = E2 + i*O2
      zr[rq] = E2r + O2i; zi[rq] = O2r - E2i;   // W[kq] = conj(E2) + i*conj(O2)
    }
  }
  asm volatile("s_waitcnt lgkmcnt(0)" ::: "memory");

  // inverse DIT, 10 stages (conjugate twiddles), natural-order output
  for (int lh = 0; lh <= 9; ++lh) {
    int h = 1 << lh;
#pragma unroll
    for (int q = 0; q < 8; ++q) {
      int m = q * 64 + lane;
      int j = m & (h - 1);
      int base = ((m >> lh) << (lh + 1)) | j;
      int ib = PADI(base), ih = PADI(base + h);
      float ur = zr[ib], ui = zi[ib];
      float vr = zr[ih], vi = zi[ih];
      int tj = PADI(j << (9 - lh));
      float twr = TWr[tj], twi = TWi[tj];
      float tx = vr * twr + vi * twi, ty = vi * twr - vr * twi;
      zr[ib] = ur + tx; zi[ib] = ui + ty;
      zr[ih] = ur - tx; zi[ih] = ui - ty;
    }
    asm volatile("s_waitcnt lgkmcnt(0)" ::: "memory");
  }

  // store y in place: y[2n] = Re z'[n], y[2n+1] = Im z'[n]
#pragma unroll
  for (int q = 0; q < 8; ++q) {
    int i4 = q * 64 + lane;
    int n0 = 2 * i4;
    int p0 = PADI(n0);
    float4 w4;
    w4.x = zr[p0]; w4.y = zi[p0];
    w4.z = zr[p0 + 1]; w4.w = zi[p0 + 1];
    *reinterpret_cast<float4*>(col + i4 * 4) = w4;
  }
}

// ---------------- transpose + split: yT[b][c][t] fp32 -> y{h,l}[b][t][c] bf16 ----------------
__global__ __launch_bounds__(256) void tysplit_kernel(
    const float* __restrict__ yT, u16t* __restrict__ yh, u16t* __restrict__ yl) {
  __shared__ float tile[64][65];
  int t0 = blockIdx.x * 64, c0 = blockIdx.y * 64, b = blockIdx.z;
  int r = threadIdx.x >> 4;
  int cc = (threadIdx.x & 15) * 4;
#pragma unroll
  for (int i = 0; i < 4; ++i) {
    int row = r + 16 * i;
    float4 w = *reinterpret_cast<const float4*>(
        yT + ((size_t)b * DMOD + c0 + row) * NSEQ + t0 + cc);
    tile[row][cc] = w.x; tile[row][cc + 1] = w.y;
    tile[row][cc + 2] = w.z; tile[row][cc + 3] = w.w;
  }
  __syncthreads();
#pragma unroll
  for (int i = 0; i < 4; ++i) {
    int tt = r + 16 * i;
    alignas(8) u16t hh[4], ll[4];
#pragma unroll
    for (int e = 0; e < 4; ++e) {
      float v = tile[cc + e][tt];
      u16t h = bf16_rtn(v);
      hh[e] = h;
      ll[e] = bf16_rtn(v - bf16f(h));
    }
    size_t o = ((size_t)b * NSEQ + t0 + tt) * DMOD + c0 + cc;
    *reinterpret_cast<ushort4*>(yh + o) = *reinterpret_cast<const ushort4*>(hh);
    *reinterpret_cast<ushort4*>(yl + o) = *reinterpret_cast<const ushort4*>(ll);
  }
}

// ---------------- scores s = h1 @ Wp2 + bp2 (K=256) ----------------
__global__ __launch_bounds__(256) void score_kernel(
    const float* __restrict__ h1, const float* __restrict__ Wp2,
    const float* __restrict__ bp2, float* __restrict__ s) {
  int tid = threadIdx.x;
  int lane = tid & 63, w = tid >> 6;
  int row = blockIdx.x * 4 + w;
  float acc = 0.f;
#pragma unroll
  for (int q = 0; q < 4; ++q) {
    int k = lane + 64 * q;
    acc = fmaf(h1[(size_t)row * 256 + k], Wp2[k], acc);
  }
#pragma unroll
  for (int off = 32; off; off >>= 1) acc += __shfl_down(acc, off);
  if (lane == 0) s[row] = acc + bp2[0];
}

// ---------------- per-batch softmax stats ----------------
__global__ __launch_bounds__(256) void softmax_stats_kernel(
    const float* __restrict__ s, float* __restrict__ bstats) {
  int b = blockIdx.x, tid = threadIdx.x;
  __shared__ float red[256];
  float m = -1e30f;
  for (int n = tid; n < NSEQ; n += 256) m = fmaxf(m, s[b * NSEQ + n]);
  red[tid] = m; __syncthreads();
  for (int o = 128; o; o >>= 1) { if (tid < o) red[tid] = fmaxf(red[tid], red[tid + o]); __syncthreads(); }
  float bm = red[0]; __syncthreads();
  float sum = 0.f;
  for (int n = tid; n < NSEQ; n += 256) sum += expf(s[b * NSEQ + n] - bm);
  red[tid] = sum; __syncthreads();
  for (int o = 128; o; o >>= 1) { if (tid < o) red[tid] += red[tid + o]; __syncthreads(); }
  if (tid == 0) { bstats[b * 2] = bm; bstats[b * 2 + 1] = red[0]; }
}

// ---------------- pooled g partials ----------------
__global__ __launch_bounds__(256) void pool_partial_kernel(
    const float* __restrict__ x, const float* __restrict__ s,
    const float* __restrict__ bstats, float* __restrict__ gpart) {
  int chunk = blockIdx.x, b = blockIdx.y;
  int tid = threadIdx.x;
  __shared__ float wsh[128];
  float bm = bstats[b * 2], inv = 1.0f / bstats[b * 2 + 1];
  int n0 = chunk * 128;
  if (tid < 128) wsh[tid] = expf(s[b * NSEQ + n0 + tid] - bm) * inv;
  __syncthreads();
  float acc[4] = {};
  for (int n = 0; n < 128; ++n) {
    float wn = wsh[n];
    const float* xr = &x[((size_t)b * NSEQ + n0 + n) * DMOD];
#pragma unroll
    for (int q = 0; q < 4; ++q) acc[q] = fmaf(wn, xr[tid + 256 * q], acc[q]);
  }
  float* gp = &gpart[((size_t)b * 16 + chunk) * DMOD];
#pragma unroll
  for (int q = 0; q < 4; ++q) gp[tid + 256 * q] = acc[q];
}

// ---------------- fused pool-reduce + MLP1 partial ----------------
__global__ __launch_bounds__(256) void pool_reduce_mlp1_kernel(
    const float* __restrict__ gpart, const float* __restrict__ Wg1,
    float* __restrict__ part1) {
  int kb = blockIdx.x, b = blockIdx.y;
  int tid = threadIdx.x;
  int k0 = kb * 64;
  __shared__ float g_s[64];
  if (tid < 64) {
    float acc = 0.f;
#pragma unroll
    for (int j = 0; j < 16; ++j)
      acc += gpart[((size_t)b * 16 + j) * DMOD + k0 + tid];
    g_s[tid] = acc;
  }
  __syncthreads();
  float acc = 0.f;
#pragma unroll 8
  for (int i = 0; i < 64; ++i)
    acc = fmaf(g_s[i], Wg1[(size_t)(k0 + i) * 256 + tid], acc);
  part1[((size_t)b * 16 + kb) * 256 + tid] = acc;
}

// ---------------- fused MLP1-reduce+gelu + MLP2 partial ----------------
__global__ __launch_bounds__(256) void mlp1red_mlp2_kernel(
    const float* __restrict__ part1, const float* __restrict__ bg1,
    const float* __restrict__ Wg2, float* __restrict__ part2) {
  int kb2 = blockIdx.x, nh = blockIdx.y, b = blockIdx.z;
  int tid = threadIdx.x;
  int k0 = kb2 * 64;
  __shared__ float hs_s[64];
  if (tid < 64) {
    float acc = bg1[k0 + tid];
#pragma unroll
    for (int j = 0; j < 16; ++j)
      acc += part1[((size_t)b * 16 + j) * 256 + k0 + tid];
    hs_s[tid] = gelu_exact(acc);
  }
  __syncthreads();
  float acc[2] = {};
#pragma unroll 8
  for (int i = 0; i < 64; ++i) {
    float hv = hs_s[i];
    const float* wr = &Wg2[(size_t)(k0 + i) * 1024 + nh * 512];
    acc[0] = fmaf(hv, wr[tid], acc[0]);
    acc[1] = fmaf(hv, wr[tid + 256], acc[1]);
  }
  float* pp = &part2[((size_t)b * 4 + kb2) * 1024 + nh * 512];
  pp[tid] = acc[0];
  pp[tid + 256] = acc[1];
}

// ---------------- anchors-reduce + cubic resize + modReLU + complex conv ----------------
__device__ __forceinline__ float keys_cubic(float x) {
  if (x >= 2.0f) return 0.0f;
  if (x >= 1.0f) return ((-0.5f * x + 2.5f) * x - 4.0f) * x + 2.0f;
  return ((1.5f * x - 2.5f) * x) * x + 1.0f;
}

__global__ __launch_bounds__(256) void gate_kernel(
    const float* __restrict__ part2, const float* __restrict__ bg2,
    const float* __restrict__ mod_bias,
    const float* __restrict__ kr5, const float* __restrict__ ki5,
    float* __restrict__ gate_out) {
  int bh = blockIdx.x;
  int tid = threadIdx.x;
  __shared__ float anch_s[64];
  __shared__ float ar_[32], ai_[32];
  __shared__ float gr[NFREQ], gi[NFREQ];
  int b = bh >> 4, h = bh & 15;
  if (tid < 64) {
    int cc = h * 64 + tid;
    float acc = bg2[cc];
#pragma unroll
    for (int j = 0; j < 4; ++j)
      acc += part2[((size_t)b * 4 + j) * 1024 + cc];
    anch_s[tid] = acc;
  }
  __syncthreads();
  if (tid < 32) {
    ar_[tid] = anch_s[tid * 2 + 0];
    ai_[tid] = anch_s[tid * 2 + 1];
  }
  __syncthreads();
  const float inv_scale = 32.0f / 1025.0f;
  for (int f = tid; f < NFREQ; f += 256) {
    float c = (f + 0.5f) * inv_scale - 0.5f;
    int j0 = (int)floorf(c) - 1;
    float wr = 0.f, wi = 0.f, wsum = 0.f;
#pragma unroll
    for (int u = 0; u < 4; ++u) {
      int j = j0 + u;
      if (j < 0 || j > 31) continue;
      float w = keys_cubic(fabsf(c - (float)j));
      wsum += w;
      wr = fmaf(w, ar_[j], wr);
      wi = fmaf(w, ai_[j], wi);
    }
    float invw = 1.0f / wsum;
    wr *= invw; wi *= invw;
    float mag = sqrtf(wr * wr + wi * wi);
    float scale = fmaxf(mag + mod_bias[f], 0.0f) / (mag + 1e-8f);
    gr[f] = wr * scale;
    gi[f] = wi * scale;
  }
  __syncthreads();
  float k_r[5], k_i[5];
#pragma unroll
  for (int j = 0; j < 5; ++j) { k_r[j] = kr5[j]; k_i[j] = ki5[j]; }
  for (int f = tid; f < NFREQ; f += 256) {
    float cr = 0.f, ci = 0.f;
#pragma unroll
    for (int j = 0; j < 5; ++j) {
      int idx = f + j - 2;
      if (idx < 0) idx += NFREQ;
      else if (idx >= NFREQ) idx -= NFREQ;
      float a = gr[idx], bb = gi[idx];
      cr = fmaf(k_r[j], a, cr); cr = fmaf(-k_i[j], bb, cr);
      ci = fmaf(k_r[j], bb, ci); ci = fmaf(k_i[j], a, ci);
    }
    gate_out[((size_t)bh * NFREQ + f) * 2 + 0] = cr;
    gate_out[((size_t)bh * NFREQ + f) * 2 + 1] = ci;
  }
}

extern "C" void kernel_launch(void* const* d_in, const int* in_sizes, int n_in,
                              void* d_out, int out_size, void* d_ws, size_t ws_size,
                              hipStream_t stream) {
  const float* x        = (const float*)d_in[0];
  const float* Wv       = (const float*)d_in[1];
  const float* bv       = (const float*)d_in[2];
  const float* Wp1      = (const float*)d_in[3];
  const float* bp1      = (const float*)d_in[4];
  const float* Wp2      = (const float*)d_in[5];
  const float* bp2      = (const float*)d_in[6];
  const float* Wg1      = (const float*)d_in[7];
  const float* bg1      = (const float*)d_in[8];
  const float* Wg2      = (const float*)d_in[9];
  const float* bg2      = (const float*)d_in[10];
  const float* mod_bias = (const float*)d_in[11];
  const float* ckr      = (const float*)d_in[12];
  const float* cki      = (const float*)d_in[13];
  const float* Wo       = (const float*)d_in[14];
  const float* bo       = (const float*)d_in[15];

  const int M = NBATCH * NSEQ;          // 8192
  const size_t MD = (size_t)M * DMOD;   // 8M elems

  // ws layout:
  u16t* x_hi = (u16t*)d_ws;             // 16 MB ; later reused as y split hi
  u16t* x_lo = x_hi + MD;               // 16 MB ; later reused as y split lo
  u16t* y_hi = x_hi;
  u16t* y_lo = x_lo;
  u16t* WT_h = (u16t*)((char*)d_ws + (size_t)32 * 1024 * 1024);  // 2 MB
  u16t* WT_l = WT_h + (size_t)1024 * 1024;                        // 2 MB
  float* part1 = (float*)WT_h;                  // 16 KB (aliases dead WT(Wp1))
  float* part2 = part1 + 4 * 16 * 256;          // 16 KB
  float* smallf = (float*)((char*)d_ws + (size_t)36 * 1024 * 1024);
  float* s       = smallf;              // 8192
  float* bstats  = s + 8192;            // 8
  float* gpart   = bstats + 8;          // 65536
  float* gateb   = gpart + 65536;       // 131200

  // d_out staging: h1 (8 MB fp32) -> vT fp32 (32 MB, in-place FFT -> yT) -> out fp32
  float* h1  = (float*)d_out;
  float* vT  = (float*)d_out;
  float* out = (float*)d_out;

  dim3 blk(256);

  // 0. split x -> bf16 hi/lo
  split_kernel<<<dim3(2048), blk, 0, stream>>>(x, x_hi, x_lo, (int)(MD / 8));
  // 1. Wp1^T split; GEMM2: h1 = gelu(x @ Wp1 + bp1)
  tsplit_kernel<<<dim3(256 / 32, 1024 / 32), blk, 0, stream>>>(Wp1, WT_h, WT_l, 1024, 256);
  mfma_gemm<true, 0><<<dim3(256 / 128, M / 128), blk, 0, stream>>>(
      x_hi, x_lo, WT_h, WT_l, bp1, h1, 256, 1024);
  // 2. scores + softmax + pooled g partials
  score_kernel<<<dim3(M / 4), blk, 0, stream>>>(h1, Wp2, bp2, s);
  softmax_stats_kernel<<<dim3(NBATCH), blk, 0, stream>>>(s, bstats);
  pool_partial_kernel<<<dim3(16, NBATCH), blk, 0, stream>>>(x, s, bstats, gpart);
  // 3. gate MLP (parallel K-split; WT(Wp1) dead -> part1/part2 alias it)
  pool_reduce_mlp1_kernel<<<dim3(16, NBATCH), blk, 0, stream>>>(gpart, Wg1, part1);
  mlp1red_mlp2_kernel<<<dim3(4, 2, NBATCH), blk, 0, stream>>>(part1, bg1, Wg2, part2);
  gate_kernel<<<dim3(NBATCH * NHEAD), blk, 0, stream>>>(part2, bg2, mod_bias, ckr, cki, gateb);
  // 4. Wv^T split; GEMM1: vT = (x @ Wv + bv)^T fp32 into d_out (h1 dead)
  tsplit_kernel<<<dim3(1024 / 32, 1024 / 32), blk, 0, stream>>>(Wv, WT_h, WT_l, 1024, 1024);
  mfma_gemm<false, 2><<<dim3(DMOD / 128, M / 128), blk, 0, stream>>>(
      x_hi, x_lo, WT_h, WT_l, bv, vT, DMOD, 1024);
  // 5. fused rFFT*gate*irFFT in place on vT -> yT
  conv_fft_kernel<<<dim3(DMOD / 4, NBATCH), blk, 0, stream>>>(vT, gateb);
  // 6. transpose+split: yT -> y split bf16 (overwrites x split; x dead)
  tysplit_kernel<<<dim3(NSEQ / 64, DMOD / 64, NBATCH), blk, 0, stream>>>(vT, y_hi, y_lo);
  // 7. Wo^T split; GEMM3: out = y @ Wo + bo (overwrites yT; dead)
  tsplit_kernel<<<dim3(1024 / 32, 1024 / 32), blk, 0, stream>>>(Wo, WT_h, WT_l, 1024, 1024);
  mfma_gemm<false, 0><<<dim3(DMOD / 128, M / 128), blk, 0, stream>>>(
      y_hi, y_lo, WT_h, WT_l, bo, out, DMOD, 1024);
}

// Round 7
// 250.250 us; speedup vs baseline: 4.3181x; 1.0661x over previous
//
#include <hip/hip_runtime.h>
#include <math.h>

#define NSEQ 2048
#define DMOD 1024
#define NBATCH 4
#define NHEAD 16
#define NFREQ 1025

typedef unsigned short u16t;
typedef __attribute__((ext_vector_type(8))) short short8;
typedef __attribute__((ext_vector_type(4))) float f32x4;

__device__ __forceinline__ float gelu_exact(float x) {
  return 0.5f * x * (1.0f + erff(x * 0.70710678118654752440f));
}
__device__ __forceinline__ u16t bf16_rtn(float x) {
  unsigned u = __float_as_uint(x);
  return (u16t)((u + 0x7FFFu + ((u >> 16) & 1u)) >> 16);
}
__device__ __forceinline__ float bf16f(u16t h) {
  return __uint_as_float(((unsigned)h) << 16);
}
__device__ __forceinline__ void gload_lds16(const u16t* g, u16t* l) {
  __builtin_amdgcn_global_load_lds(
      (const __attribute__((address_space(1))) void*)g,
      (__attribute__((address_space(3))) void*)l, 16, 0, 0);
}

// ---------------- elementwise split fp32 -> bf16 hi/lo ----------------
__global__ __launch_bounds__(256) void split_kernel(const float* __restrict__ in,
    u16t* __restrict__ hi, u16t* __restrict__ lo, int n8) {
  for (int i = blockIdx.x * blockDim.x + threadIdx.x; i < n8; i += gridDim.x * blockDim.x) {
    const float4* p = reinterpret_cast<const float4*>(in + (size_t)i * 8);
    float4 a = p[0], b = p[1];
    float vv[8] = {a.x, a.y, a.z, a.w, b.x, b.y, b.z, b.w};
    alignas(16) u16t th[8];
    alignas(16) u16t tl[8];
#pragma unroll
    for (int e = 0; e < 8; ++e) {
      u16t h = bf16_rtn(vv[e]);
      th[e] = h;
      tl[e] = bf16_rtn(vv[e] - bf16f(h));
    }
    *reinterpret_cast<uint4*>(hi + (size_t)i * 8) = *reinterpret_cast<const uint4*>(th);
    *reinterpret_cast<uint4*>(lo + (size_t)i * 8) = *reinterpret_cast<const uint4*>(tl);
  }
}

// ---------------- transpose + split weights: W[K][N] -> T{h,l}[N][K] ----------------
__global__ __launch_bounds__(256) void tsplit_kernel(const float* __restrict__ W,
    u16t* __restrict__ Th, u16t* __restrict__ Tl, int K, int N) {
  __shared__ float tile[32][33];
  int k0 = blockIdx.y * 32, n0 = blockIdx.x * 32;
  int r = threadIdx.x >> 5, c = threadIdx.x & 31;
#pragma unroll
  for (int i = 0; i < 4; ++i)
    tile[r + 8 * i][c] = W[(size_t)(k0 + r + 8 * i) * N + n0 + c];
  __syncthreads();
#pragma unroll
  for (int i = 0; i < 4; ++i) {
    int rr = r + 8 * i;
    float v = tile[c][rr];
    u16t h = bf16_rtn(v);
    Th[(size_t)(n0 + rr) * K + k0 + c] = h;
    Tl[(size_t)(n0 + rr) * K + k0 + c] = bf16_rtn(v - bf16f(h));
  }
}

// ---------------- split-bf16 MFMA GEMM ----------------
template<bool GELU, int OUTMODE>
__global__ __launch_bounds__(256) void mfma_gemm(
    const u16t* __restrict__ Ah_g, const u16t* __restrict__ Al_g,
    const u16t* __restrict__ Bh_g, const u16t* __restrict__ Bl_g,
    const float* __restrict__ bias,
    float* __restrict__ Cf,
    int N, int K) {
  __shared__ u16t Ahs[128 * 64], Als[128 * 64], Bhs[128 * 64], Bls[128 * 64]; // 64 KB
  const int tid = threadIdx.x;
  const int lane = tid & 63, wave = tid >> 6;
  const int lr = lane & 15, lg = lane >> 4;
  const int wm0 = (wave >> 1) * 64, wn0 = (wave & 1) * 64;
  const int m0 = blockIdx.y * 128, n0 = blockIdx.x * 128;

  f32x4 acc[4][4];
#pragma unroll
  for (int i = 0; i < 4; ++i)
#pragma unroll
    for (int j = 0; j < 4; ++j) acc[i][j] = 0.0f;

  for (int k0 = 0; k0 < K; k0 += 64) {
#pragma unroll
    for (int q = 0; q < 4; ++q) {
      int cid = q * 256 + tid;
      int row = cid >> 3, grp = cid & 7;
      int koff = k0 + ((grp ^ (row & 7)) << 3);
      size_t ea = (size_t)(m0 + row) * K + koff;
      size_t eb = (size_t)(n0 + row) * K + koff;
      int lbase = q * 2048 + wave * 512;
      gload_lds16(Ah_g + ea, Ahs + lbase);
      gload_lds16(Al_g + ea, Als + lbase);
      gload_lds16(Bh_g + eb, Bhs + lbase);
      gload_lds16(Bl_g + eb, Bls + lbase);
    }
    __syncthreads();
#pragma unroll
    for (int kf = 0; kf < 2; ++kf) {
      short8 ah[4], al[4];
#pragma unroll
      for (int mi = 0; mi < 4; ++mi) {
        int r_ = wm0 + mi * 16 + lr;
        int g = (kf * 4 + lg) ^ (r_ & 7);
        ah[mi] = *reinterpret_cast<const short8*>(&Ahs[r_ * 64 + g * 8]);
        al[mi] = *reinterpret_cast<const short8*>(&Als[r_ * 64 + g * 8]);
      }
#pragma unroll
      for (int ni = 0; ni < 4; ++ni) {
        int r_ = wn0 + ni * 16 + lr;
        int g = (kf * 4 + lg) ^ (r_ & 7);
        short8 bh8 = *reinterpret_cast<const short8*>(&Bhs[r_ * 64 + g * 8]);
        short8 bl8 = *reinterpret_cast<const short8*>(&Bls[r_ * 64 + g * 8]);
#pragma unroll
        for (int mi = 0; mi < 4; ++mi) {
          acc[mi][ni] = __builtin_amdgcn_mfma_f32_16x16x32_bf16(ah[mi], bh8, acc[mi][ni], 0, 0, 0);
          acc[mi][ni] = __builtin_amdgcn_mfma_f32_16x16x32_bf16(ah[mi], bl8, acc[mi][ni], 0, 0, 0);
          acc[mi][ni] = __builtin_amdgcn_mfma_f32_16x16x32_bf16(al[mi], bh8, acc[mi][ni], 0, 0, 0);
        }
      }
    }
    __syncthreads();
  }
#pragma unroll
  for (int mi = 0; mi < 4; ++mi)
#pragma unroll
    for (int ni = 0; ni < 4; ++ni) {
      int col = n0 + wn0 + ni * 16 + lr;
      float bv = bias[col];
      f32x4 a = acc[mi][ni];
      if (OUTMODE == 2) {
        int mbase = m0 + wm0 + mi * 16 + lg * 4;
        int b = mbase >> 11, ss = mbase & 2047;
        float4 o4;
        o4.x = a[0] + bv; o4.y = a[1] + bv; o4.z = a[2] + bv; o4.w = a[3] + bv;
        *reinterpret_cast<float4*>(Cf + (size_t)b * (DMOD * NSEQ) + (size_t)col * NSEQ + ss) = o4;
      } else {
#pragma unroll
        for (int r = 0; r < 4; ++r) {
          int row = m0 + wm0 + mi * 16 + lg * 4 + r;
          float val = a[r] + bv;
          if (GELU) val = gelu_exact(val);
          Cf[(size_t)row * N + col] = val;
        }
      }
    }
}

// ---------------- fused rFFT * gate * irFFT, register-resident FFT ----------------
// Each wave owns one column; thread holds val[j] = z[j*64+lane] (16 complex in VGPRs).
// Strides 512..64 in-register; 32..1 via __shfl_xor; middle (untangle*gate*retangle)
// through per-wave LDS with PADI padding (only LDS phase left).
#define PADI(i) ((i) + ((i) >> 5))

template<int HJ, int TWS>
__device__ __forceinline__ void fwd_reg_stage(float* vr, float* vi,
    const float* TWr, const float* TWi, int lane) {
  float twr_[HJ], twi_[HJ];
#pragma unroll
  for (int t = 0; t < HJ; ++t) {
    int m = (t * 64 + lane) * TWS;
    twr_[t] = TWr[PADI(m)]; twi_[t] = TWi[PADI(m)];
  }
#pragma unroll
  for (int j = 0; j < 16; ++j) {
    if (j & HJ) continue;
    int t = j & (HJ - 1);
    float ur = vr[j], ui = vi[j];
    float wr = vr[j + HJ], wi = vi[j + HJ];
    float dr = ur - wr, di = ui - wi;
    vr[j] = ur + wr; vi[j] = ui + wi;
    vr[j + HJ] = dr * twr_[t] - di * twi_[t];
    vi[j + HJ] = dr * twi_[t] + di * twr_[t];
  }
}

template<int S, int TWS>
__device__ __forceinline__ void fwd_lane_stage(float* vr, float* vi,
    const float* TWr, const float* TWi, int lane) {
  float twr_ = 1.0f, twi_ = 0.0f;
  if (S > 1) {
    int m = (lane & (S - 1)) * TWS;
    twr_ = TWr[PADI(m)]; twi_ = TWi[PADI(m)];
  }
  bool hi = (lane & S) != 0;
#pragma unroll
  for (int j = 0; j < 16; ++j) {
    float or_ = __shfl_xor(vr[j], S, 64);
    float oi_ = __shfl_xor(vi[j], S, 64);
    float sr = vr[j] + or_, si_ = vi[j] + oi_;
    float dr = or_ - vr[j], di = oi_ - vi[j];
    float rr = dr * twr_ - di * twi_;
    float ri = dr * twi_ + di * twr_;
    vr[j] = hi ? rr : sr;
    vi[j] = hi ? ri : si_;
  }
}

template<int S, int TWS>
__device__ __forceinline__ void inv_lane_stage(float* vr, float* vi,
    const float* TWr, const float* TWi, int lane) {
  float twr_ = 1.0f, twi_ = 0.0f;
  if (S > 1) {
    int m = (lane & (S - 1)) * TWS;
    twr_ = TWr[PADI(m)]; twi_ = -TWi[PADI(m)];
  }
  bool hi = (lane & S) != 0;
#pragma unroll
  for (int j = 0; j < 16; ++j) {
    float xr = vr[j], xi = vi[j];
    if (S > 1) {
      float pr = xr * twr_ - xi * twi_;
      float pi = xr * twi_ + xi * twr_;
      xr = hi ? pr : xr;
      xi = hi ? pi : xi;
    }
    float or_ = __shfl_xor(xr, S, 64);
    float oi_ = __shfl_xor(xi, S, 64);
    vr[j] = hi ? (or_ - xr) : (xr + or_);
    vi[j] = hi ? (oi_ - xi) : (xi + oi_);
  }
}

template<int HJ, int TWS>
__device__ __forceinline__ void inv_reg_stage(float* vr, float* vi,
    const float* TWr, const float* TWi, int lane) {
  float twr_[HJ], twi_[HJ];
#pragma unroll
  for (int t = 0; t < HJ; ++t) {
    int m = (t * 64 + lane) * TWS;
    twr_[t] = TWr[PADI(m)]; twi_[t] = -TWi[PADI(m)];
  }
#pragma unroll
  for (int j = 0; j < 16; ++j) {
    if (j & HJ) continue;
    int t = j & (HJ - 1);
    float ur = vr[j], ui = vi[j];
    float br = vr[j + HJ], bi = vi[j + HJ];
    float wr = br * twr_[t] - bi * twi_[t];
    float wi = br * twi_[t] + bi * twr_[t];
    vr[j] = ur + wr; vi[j] = ui + wi;
    vr[j + HJ] = ur - wr; vi[j + HJ] = ui - wi;
  }
}

__global__ __launch_bounds__(256) void conv_fft_kernel(
    float* __restrict__ vio, const float* __restrict__ gateb) {
  __shared__ float Zr[4][1056], Zi[4][1056];   // per-wave middle buffer (33 KB)
  __shared__ float TWr[528], TWi[528];         // e^{-2pi i m/1024}
  const int tid = threadIdx.x;
  const int lane = tid & 63, wave = tid >> 6;
  const int c0 = blockIdx.x * 4;
  const int b = blockIdx.y;
  const int bh = b * NHEAD + (c0 >> 6);
  const float* gate_bh = gateb + (size_t)bh * NFREQ * 2;

#pragma unroll
  for (int q = 0; q < 2; ++q) {
    int m = q * 256 + tid;
    float si, co;
    sincosf(-3.14159265358979323846f * (float)m * (1.0f / 512.0f), &si, &co);
    TWr[PADI(m)] = co; TWi[PADI(m)] = si;
  }
  __syncthreads();

  float* zr = Zr[wave];
  float* zi = Zi[wave];
  float* col = vio + ((size_t)b * DMOD + (c0 + wave)) * NSEQ;

  float vr[16], vi[16];
  // load packed z[n] = v[2n] + i v[2n+1], val[j] = z[j*64+lane]
#pragma unroll
  for (int j = 0; j < 16; ++j) {
    float2 w2 = *reinterpret_cast<const float2*>(col + 2 * (j * 64 + lane));
    vr[j] = w2.x; vi[j] = w2.y;
  }

  // ---- forward DIF (natural -> bit-reversed) ----
  fwd_reg_stage<8, 1>(vr, vi, TWr, TWi, lane);     // stride 512
  fwd_reg_stage<4, 2>(vr, vi, TWr, TWi, lane);     // stride 256
  fwd_reg_stage<2, 4>(vr, vi, TWr, TWi, lane);     // stride 128
  fwd_reg_stage<1, 8>(vr, vi, TWr, TWi, lane);     // stride 64
  fwd_lane_stage<32, 16>(vr, vi, TWr, TWi, lane);  // stride 32
  fwd_lane_stage<16, 32>(vr, vi, TWr, TWi, lane);
  fwd_lane_stage<8, 64>(vr, vi, TWr, TWi, lane);
  fwd_lane_stage<4, 128>(vr, vi, TWr, TWi, lane);
  fwd_lane_stage<2, 256>(vr, vi, TWr, TWi, lane);
  fwd_lane_stage<1, 0>(vr, vi, TWr, TWi, lane);    // stride 1 (tw = 1)

  // dump to LDS, natural storage order p = j*64+lane (holds Z[bitrev(p)])
#pragma unroll
  for (int j = 0; j < 16; ++j) {
    int p = PADI(j * 64 + lane);
    zr[p] = vr[j]; zi[p] = vi[j];
  }
  asm volatile("s_waitcnt lgkmcnt(0)" ::: "memory");

  // untangle -> X[k]; Y = X*G/1024; retangle -> stored bit-reversed
  const float s1 = 1.0f / 1024.0f;
#pragma unroll
  for (int q = 0; q < 8; ++q) {
    int k = q * 64 + lane;
    if (k == 0) {
      float z0r = zr[0], z0i = zi[0];
      float X0 = z0r + z0i;
      float XN = z0r - z0i;
      float2 G0 = *reinterpret_cast<const float2*>(gate_bh + 0);
      float2 GN = *reinterpret_cast<const float2*>(gate_bh + 1024 * 2);
      float y0 = X0 * G0.x * s1;    // irfft uses Re only at DC/Nyquist
      float yN = XN * GN.x * s1;
      zr[0] = 0.5f * (y0 + yN); zi[0] = 0.5f * (y0 - yN);
      // k = 512: X = conj(Z[rev(512)=1]); W = conj(Y)
      float zmr = zr[1], zmi = zi[1];
      float X5r = zmr, X5i = -zmi;
      float2 G5 = *reinterpret_cast<const float2*>(gate_bh + 512 * 2);
      float Y5r = (X5r * G5.x - X5i * G5.y) * s1;
      float Y5i = (X5r * G5.y + X5i * G5.x) * s1;
      zr[1] = Y5r; zi[1] = -Y5i;
    } else {
      int kq = 1024 - k;
      int rp = PADI((int)(__brev((unsigned)k) >> 22));
      int rq = PADI((int)(__brev((unsigned)kq) >> 22));
      float Zkr = zr[rp], Zki = zi[rp];
      float Zqr = zr[rq], Zqi = zi[rq];
      float Er = 0.5f * (Zkr + Zqr), Ei = 0.5f * (Zki - Zqi);
      float Odr = 0.5f * (Zki + Zqi), Odi = -0.5f * (Zkr - Zqr);
      float ti, tr;
      sincosf(-3.14159265358979323846f * (float)k * (1.0f / 1024.0f), &ti, &tr);
      float Pr = Odr * tr - Odi * ti, Pi = Odr * ti + Odi * tr;
      float Xkr = Er + Pr, Xki = Ei + Pi;
      float Xqr = Er - Pr, Xqi = -(Ei - Pi);
      float2 Gk = *reinterpret_cast<const float2*>(gate_bh + k * 2);
      float2 Gq = *reinterpret_cast<const float2*>(gate_bh + kq * 2);
      float Ykr = (Xkr * Gk.x - Xki * Gk.y) * s1;
      float Yki = (Xkr * Gk.y + Xki * Gk.x) * s1;
      float Yqr = (Xqr * Gq.x - Xqi * Gq.y) * s1;
      float Yqi = (Xqr * Gq.y + Xqi * Gq.x) * s1;
      float E2r = 0.5f * (Ykr + Yqr), E2i = 0.5f * (Yki - Yqi);
      float D2r = 0.5f * (Ykr - Yqr), D2i = 0.5f * (Yki + Yqi);
      float O2r = D2r * tr + D2i * ti, O2i = D2i * tr - D2r * ti;
      zr[rp] = E2r - O2i; zi[rp] = E2i + O2r;   // W[k]  = E2 + i*O2
      zr[rq] = E2r + O2i; zi[rq] = O2r - E2i;   // W[kq] = conj(E2) + i*conj(O2)
    }
  }
  asm volatile("s_waitcnt lgkmcnt(0)" ::: "memory");

  // reload bit-reversed storage into registers
#pragma unroll
  for (int j = 0; j < 16; ++j) {
    int p = PADI(j * 64 + lane);
    vr[j] = zr[p]; vi[j] = zi[p];
  }
  asm volatile("s_waitcnt lgkmcnt(0)" ::: "memory");

  // ---- inverse DIT (bit-reversed -> natural) ----
  inv_lane_stage<1, 0>(vr, vi, TWr, TWi, lane);    // stride 1
  inv_lane_stage<2, 256>(vr, vi, TWr, TWi, lane);
  inv_lane_stage<4, 128>(vr, vi, TWr, TWi, lane);
  inv_lane_stage<8, 64>(vr, vi, TWr, TWi, lane);
  inv_lane_stage<16, 32>(vr, vi, TWr, TWi, lane);
  inv_lane_stage<32, 16>(vr, vi, TWr, TWi, lane);  // stride 32
  inv_reg_stage<1, 8>(vr, vi, TWr, TWi, lane);     // stride 64
  inv_reg_stage<2, 4>(vr, vi, TWr, TWi, lane);     // stride 128
  inv_reg_stage<4, 2>(vr, vi, TWr, TWi, lane);     // stride 256
  inv_reg_stage<8, 1>(vr, vi, TWr, TWi, lane);     // stride 512

  // store y in place: y[2n] = Re z'[n], y[2n+1] = Im z'[n]
#pragma unroll
  for (int j = 0; j < 16; ++j) {
    *reinterpret_cast<float2*>(col + 2 * (j * 64 + lane)) = make_float2(vr[j], vi[j]);
  }
}

// ---------------- transpose + split: yT[b][c][t] fp32 -> y{h,l}[b][t][c] bf16 ----------------
__global__ __launch_bounds__(256) void tysplit_kernel(
    const float* __restrict__ yT, u16t* __restrict__ yh, u16t* __restrict__ yl) {
  __shared__ float tile[64][65];
  int t0 = blockIdx.x * 64, c0 = blockIdx.y * 64, b = blockIdx.z;
  int r = threadIdx.x >> 4;
  int cc = (threadIdx.x & 15) * 4;
#pragma unroll
  for (int i = 0; i < 4; ++i) {
    int row = r + 16 * i;
    float4 w = *reinterpret_cast<const float4*>(
        yT + ((size_t)b * DMOD + c0 + row) * NSEQ + t0 + cc);
    tile[row][cc] = w.x; tile[row][cc + 1] = w.y;
    tile[row][cc + 2] = w.z; tile[row][cc + 3] = w.w;
  }
  __syncthreads();
#pragma unroll
  for (int i = 0; i < 4; ++i) {
    int tt = r + 16 * i;
    alignas(8) u16t hh[4], ll[4];
#pragma unroll
    for (int e = 0; e < 4; ++e) {
      float v = tile[cc + e][tt];
      u16t h = bf16_rtn(v);
      hh[e] = h;
      ll[e] = bf16_rtn(v - bf16f(h));
    }
    size_t o = ((size_t)b * NSEQ + t0 + tt) * DMOD + c0 + cc;
    *reinterpret_cast<ushort4*>(yh + o) = *reinterpret_cast<const ushort4*>(hh);
    *reinterpret_cast<ushort4*>(yl + o) = *reinterpret_cast<const ushort4*>(ll);
  }
}

// ---------------- scores s = h1 @ Wp2 + bp2 (K=256) ----------------
__global__ __launch_bounds__(256) void score_kernel(
    const float* __restrict__ h1, const float* __restrict__ Wp2,
    const float* __restrict__ bp2, float* __restrict__ s) {
  int tid = threadIdx.x;
  int lane = tid & 63, w = tid >> 6;
  int row = blockIdx.x * 4 + w;
  float acc = 0.f;
#pragma unroll
  for (int q = 0; q < 4; ++q) {
    int k = lane + 64 * q;
    acc = fmaf(h1[(size_t)row * 256 + k], Wp2[k], acc);
  }
#pragma unroll
  for (int off = 32; off; off >>= 1) acc += __shfl_down(acc, off);
  if (lane == 0) s[row] = acc + bp2[0];
}

// ---------------- per-batch softmax stats ----------------
__global__ __launch_bounds__(256) void softmax_stats_kernel(
    const float* __restrict__ s, float* __restrict__ bstats) {
  int b = blockIdx.x, tid = threadIdx.x;
  __shared__ float red[256];
  float m = -1e30f;
  for (int n = tid; n < NSEQ; n += 256) m = fmaxf(m, s[b * NSEQ + n]);
  red[tid] = m; __syncthreads();
  for (int o = 128; o; o >>= 1) { if (tid < o) red[tid] = fmaxf(red[tid], red[tid + o]); __syncthreads(); }
  float bm = red[0]; __syncthreads();
  float sum = 0.f;
  for (int n = tid; n < NSEQ; n += 256) sum += expf(s[b * NSEQ + n] - bm);
  red[tid] = sum; __syncthreads();
  for (int o = 128; o; o >>= 1) { if (tid < o) red[tid] += red[tid + o]; __syncthreads(); }
  if (tid == 0) { bstats[b * 2] = bm; bstats[b * 2 + 1] = red[0]; }
}

// ---------------- pooled g partials ----------------
__global__ __launch_bounds__(256) void pool_partial_kernel(
    const float* __restrict__ x, const float* __restrict__ s,
    const float* __restrict__ bstats, float* __restrict__ gpart) {
  int chunk = blockIdx.x, b = blockIdx.y;
  int tid = threadIdx.x;
  __shared__ float wsh[128];
  float bm = bstats[b * 2], inv = 1.0f / bstats[b * 2 + 1];
  int n0 = chunk * 128;
  if (tid < 128) wsh[tid] = expf(s[b * NSEQ + n0 + tid] - bm) * inv;
  __syncthreads();
  float acc[4] = {};
  for (int n = 0; n < 128; ++n) {
    float wn = wsh[n];
    const float* xr = &x[((size_t)b * NSEQ + n0 + n) * DMOD];
#pragma unroll
    for (int q = 0; q < 4; ++q) acc[q] = fmaf(wn, xr[tid + 256 * q], acc[q]);
  }
  float* gp = &gpart[((size_t)b * 16 + chunk) * DMOD];
#pragma unroll
  for (int q = 0; q < 4; ++q) gp[tid + 256 * q] = acc[q];
}

// ---------------- fused pool-reduce + MLP1 partial ----------------
__global__ __launch_bounds__(256) void pool_reduce_mlp1_kernel(
    const float* __restrict__ gpart, const float* __restrict__ Wg1,
    float* __restrict__ part1) {
  int kb = blockIdx.x, b = blockIdx.y;
  int tid = threadIdx.x;
  int k0 = kb * 64;
  __shared__ float g_s[64];
  if (tid < 64) {
    float acc = 0.f;
#pragma unroll
    for (int j = 0; j < 16; ++j)
      acc += gpart[((size_t)b * 16 + j) * DMOD + k0 + tid];
    g_s[tid] = acc;
  }
  __syncthreads();
  float acc = 0.f;
#pragma unroll 8
  for (int i = 0; i < 64; ++i)
    acc = fmaf(g_s[i], Wg1[(size_t)(k0 + i) * 256 + tid], acc);
  part1[((size_t)b * 16 + kb) * 256 + tid] = acc;
}

// ---------------- fused MLP1-reduce+gelu + MLP2 partial ----------------
__global__ __launch_bounds__(256) void mlp1red_mlp2_kernel(
    const float* __restrict__ part1, const float* __restrict__ bg1,
    const float* __restrict__ Wg2, float* __restrict__ part2) {
  int kb2 = blockIdx.x, nh = blockIdx.y, b = blockIdx.z;
  int tid = threadIdx.x;
  int k0 = kb2 * 64;
  __shared__ float hs_s[64];
  if (tid < 64) {
    float acc = bg1[k0 + tid];
#pragma unroll
    for (int j = 0; j < 16; ++j)
      acc += part1[((size_t)b * 16 + j) * 256 + k0 + tid];
    hs_s[tid] = gelu_exact(acc);
  }
  __syncthreads();
  float acc[2] = {};
#pragma unroll 8
  for (int i = 0; i < 64; ++i) {
    float hv = hs_s[i];
    const float* wr = &Wg2[(size_t)(k0 + i) * 1024 + nh * 512];
    acc[0] = fmaf(hv, wr[tid], acc[0]);
    acc[1] = fmaf(hv, wr[tid + 256], acc[1]);
  }
  float* pp = &part2[((size_t)b * 4 + kb2) * 1024 + nh * 512];
  pp[tid] = acc[0];
  pp[tid + 256] = acc[1];
}

// ---------------- anchors-reduce + cubic resize + modReLU + complex conv ----------------
__device__ __forceinline__ float keys_cubic(float x) {
  if (x >= 2.0f) return 0.0f;
  if (x >= 1.0f) return ((-0.5f * x + 2.5f) * x - 4.0f) * x + 2.0f;
  return ((1.5f * x - 2.5f) * x) * x + 1.0f;
}

__global__ __launch_bounds__(256) void gate_kernel(
    const float* __restrict__ part2, const float* __restrict__ bg2,
    const float* __restrict__ mod_bias,
    const float* __restrict__ kr5, const float* __restrict__ ki5,
    float* __restrict__ gate_out) {
  int bh = blockIdx.x;
  int tid = threadIdx.x;
  __shared__ float anch_s[64];
  __shared__ float ar_[32], ai_[32];
  __shared__ float gr[NFREQ], gi[NFREQ];
  int b = bh >> 4, h = bh & 15;
  if (tid < 64) {
    int cc = h * 64 + tid;
    float acc = bg2[cc];
#pragma unroll
    for (int j = 0; j < 4; ++j)
      acc += part2[((size_t)b * 4 + j) * 1024 + cc];
    anch_s[tid] = acc;
  }
  __syncthreads();
  if (tid < 32) {
    ar_[tid] = anch_s[tid * 2 + 0];
    ai_[tid] = anch_s[tid * 2 + 1];
  }
  __syncthreads();
  const float inv_scale = 32.0f / 1025.0f;
  for (int f = tid; f < NFREQ; f += 256) {
    float c = (f + 0.5f) * inv_scale - 0.5f;
    int j0 = (int)floorf(c) - 1;
    float wr = 0.f, wi = 0.f, wsum = 0.f;
#pragma unroll
    for (int u = 0; u < 4; ++u) {
      int j = j0 + u;
      if (j < 0 || j > 31) continue;
      float w = keys_cubic(fabsf(c - (float)j));
      wsum += w;
      wr = fmaf(w, ar_[j], wr);
      wi = fmaf(w, ai_[j], wi);
    }
    float invw = 1.0f / wsum;
    wr *= invw; wi *= invw;
    float mag = sqrtf(wr * wr + wi * wi);
    float scale = fmaxf(mag + mod_bias[f], 0.0f) / (mag + 1e-8f);
    gr[f] = wr * scale;
    gi[f] = wi * scale;
  }
  __syncthreads();
  float k_r[5], k_i[5];
#pragma unroll
  for (int j = 0; j < 5; ++j) { k_r[j] = kr5[j]; k_i[j] = ki5[j]; }
  for (int f = tid; f < NFREQ; f += 256) {
    float cr = 0.f, ci = 0.f;
#pragma unroll
    for (int j = 0; j < 5; ++j) {
      int idx = f + j - 2;
      if (idx < 0) idx += NFREQ;
      else if (idx >= NFREQ) idx -= NFREQ;
      float a = gr[idx], bb = gi[idx];
      cr = fmaf(k_r[j], a, cr); cr = fmaf(-k_i[j], bb, cr);
      ci = fmaf(k_r[j], bb, ci); ci = fmaf(k_i[j], a, ci);
    }
    gate_out[((size_t)bh * NFREQ + f) * 2 + 0] = cr;
    gate_out[((size_t)bh * NFREQ + f) * 2 + 1] = ci;
  }
}

extern "C" void kernel_launch(void* const* d_in, const int* in_sizes, int n_in,
                              void* d_out, int out_size, void* d_ws, size_t ws_size,
                              hipStream_t stream) {
  const float* x        = (const float*)d_in[0];
  const float* Wv       = (const float*)d_in[1];
  const float* bv       = (const float*)d_in[2];
  const float* Wp1      = (const float*)d_in[3];
  const float* bp1      = (const float*)d_in[4];
  const float* Wp2      = (const float*)d_in[5];
  const float* bp2      = (const float*)d_in[6];
  const float* Wg1      = (const float*)d_in[7];
  const float* bg1      = (const float*)d_in[8];
  const float* Wg2      = (const float*)d_in[9];
  const float* bg2      = (const float*)d_in[10];
  const float* mod_bias = (const float*)d_in[11];
  const float* ckr      = (const float*)d_in[12];
  const float* cki      = (const float*)d_in[13];
  const float* Wo       = (const float*)d_in[14];
  const float* bo       = (const float*)d_in[15];

  const int M = NBATCH * NSEQ;          // 8192
  const size_t MD = (size_t)M * DMOD;   // 8M elems

  // ws layout:
  u16t* x_hi = (u16t*)d_ws;             // 16 MB ; later reused as y split hi
  u16t* x_lo = x_hi + MD;               // 16 MB ; later reused as y split lo
  u16t* y_hi = x_hi;
  u16t* y_lo = x_lo;
  u16t* WT_h = (u16t*)((char*)d_ws + (size_t)32 * 1024 * 1024);  // 2 MB
  u16t* WT_l = WT_h + (size_t)1024 * 1024;                        // 2 MB
  float* part1 = (float*)WT_h;                  // 16 KB (aliases dead WT(Wp1))
  float* part2 = part1 + 4 * 16 * 256;          // 16 KB
  float* smallf = (float*)((char*)d_ws + (size_t)36 * 1024 * 1024);
  float* s       = smallf;              // 8192
  float* bstats  = s + 8192;            // 8
  float* gpart   = bstats + 8;          // 65536
  float* gateb   = gpart + 65536;       // 131200

  // d_out staging: h1 (8 MB fp32) -> vT fp32 (32 MB, in-place FFT -> yT) -> out fp32
  float* h1  = (float*)d_out;
  float* vT  = (float*)d_out;
  float* out = (float*)d_out;

  dim3 blk(256);

  // 0. split x -> bf16 hi/lo
  split_kernel<<<dim3(2048), blk, 0, stream>>>(x, x_hi, x_lo, (int)(MD / 8));
  // 1. Wp1^T split; GEMM2: h1 = gelu(x @ Wp1 + bp1)
  tsplit_kernel<<<dim3(256 / 32, 1024 / 32), blk, 0, stream>>>(Wp1, WT_h, WT_l, 1024, 256);
  mfma_gemm<true, 0><<<dim3(256 / 128, M / 128), blk, 0, stream>>>(
      x_hi, x_lo, WT_h, WT_l, bp1, h1, 256, 1024);
  // 2. scores + softmax + pooled g partials
  score_kernel<<<dim3(M / 4), blk, 0, stream>>>(h1, Wp2, bp2, s);
  softmax_stats_kernel<<<dim3(NBATCH), blk, 0, stream>>>(s, bstats);
  pool_partial_kernel<<<dim3(16, NBATCH), blk, 0, stream>>>(x, s, bstats, gpart);
  // 3. gate MLP (parallel K-split; WT(Wp1) dead -> part1/part2 alias it)
  pool_reduce_mlp1_kernel<<<dim3(16, NBATCH), blk, 0, stream>>>(gpart, Wg1, part1);
  mlp1red_mlp2_kernel<<<dim3(4, 2, NBATCH), blk, 0, stream>>>(part1, bg1, Wg2, part2);
  gate_kernel<<<dim3(NBATCH * NHEAD), blk, 0, stream>>>(part2, bg2, mod_bias, ckr, cki, gateb);
  // 4. Wv^T split; GEMM1: vT = (x @ Wv + bv)^T fp32 into d_out (h1 dead)
  tsplit_kernel<<<dim3(1024 / 32, 1024 / 32), blk, 0, stream>>>(Wv, WT_h, WT_l, 1024, 1024);
  mfma_gemm<false, 2><<<dim3(DMOD / 128, M / 128), blk, 0, stream>>>(
      x_hi, x_lo, WT_h, WT_l, bv, vT, DMOD, 1024);
  // 5. fused rFFT*gate*irFFT in place on vT -> yT
  conv_fft_kernel<<<dim3(DMOD / 4, NBATCH), blk, 0, stream>>>(vT, gateb);
  // 6. transpose+split: yT -> y split bf16 (overwrites x split; x dead)
  tysplit_kernel<<<dim3(NSEQ / 64, DMOD / 64, NBATCH), blk, 0, stream>>>(vT, y_hi, y_lo);
  // 7. Wo^T split; GEMM3: out = y @ Wo + bo (overwrites yT; dead)
  tsplit_kernel<<<dim3(1024 / 32, 1024 / 32), blk, 0, stream>>>(Wo, WT_h, WT_l, 1024, 1024);
  mfma_gemm<false, 0><<<dim3(DMOD / 128, M / 128), blk, 0, stream>>>(
      y_hi, y_lo, WT_h, WT_l, bo, out, DMOD, 1024);
}